// Round 12
// baseline (1163.326 us; speedup 1.0000x reference)
//
#include <hip/hip_runtime.h>
#include <cmath>
#include <type_traits>

#define NL 16
#define TBL_N (1u << 19)
#define HID 64
#define NDL 6   // dense (coarse) levels

typedef float f4v __attribute__((ext_vector_type(4)));
typedef float f2v __attribute__((ext_vector_type(2)));
typedef short s8v __attribute__((ext_vector_type(8)));
typedef unsigned int u32;
typedef unsigned short u16;

struct Res16 { float r[NL]; };
struct DenseP { int R[NDL]; int off[NDL]; int total; };

__device__ __host__ __forceinline__ unsigned short f2bf(float f) {
    unsigned u = __builtin_bit_cast(unsigned, f);
    unsigned r = (u + 0x7FFFu + ((u >> 16) & 1u)) >> 16;   // RNE
    return (unsigned short)r;
}
__device__ __forceinline__ u32 pack_bf(float a, float b) {
    return (u32)f2bf(a) | ((u32)f2bf(b) << 16);
}
__device__ __forceinline__ void corner_vals(unsigned v, float& f0, float& f1) {
    f0 = __uint_as_float(v << 16);
    f1 = __uint_as_float(v & 0xffff0000u);
}
__device__ __forceinline__ void corner_vals(float2 v, float& f0, float& f1) {
    f0 = v.x; f1 = v.y;
}

__global__ __launch_bounds__(256) void repack_bf16(const float* __restrict__ src,
                                                   unsigned* __restrict__ dst, int n) {
    int i = blockIdx.x * blockDim.x + threadIdx.x;
    if (i >= n) return;
    f2v v = __builtin_nontemporal_load((const f2v*)src + i);
    dst[i] = pack_bf(v.x, v.y);
}

// ======================= Build dense z-pair tables for levels 0..5 =========
__global__ __launch_bounds__(256) void build_dense(
    const u32* __restrict__ tbl, uint2* __restrict__ dense, DenseP dp)
{
    int e = blockIdx.x * 256 + threadIdx.x;
    if (e >= dp.total) return;
    int l = 0;
    #pragma unroll
    for (int i = 1; i < NDL; i++) if (e >= dp.off[i]) l = i;
    int cell = e - dp.off[l];
    int R = dp.R[l];
    int Z = cell % R; int t = cell / R; int Y = t % R; int X = t / R;
    u32 hy = (u32)Y * 2654435761u;
    u32 hz0 = (u32)Z * 805459861u;
    u32 hz1 = hz0 + 805459861u;
    u32 i0 = ((u32)X ^ hy ^ hz0) & (TBL_N - 1u);
    u32 i1 = ((u32)X ^ hy ^ hz1) & (TBL_N - 1u);
    const u32* base = tbl + (size_t)l * TBL_N;
    dense[e] = make_uint2(base[i0], base[i1]);
}

// ======================= Kernel E: corner-parallel encode ==================
// 8 lanes per point: one gather instruction covers all 8 corners of a point,
// so X-pair same-line corners (~94%) merge in the TA/MSHR within the
// instruction. 3x shfl_xor reduce; lane sub==0 stores. blockIdx.y = level.
__global__ __launch_bounds__(256) void nerf_encode(
    const float* __restrict__ x,
    const unsigned* __restrict__ tbl,
    const uint2* __restrict__ dense,
    u32* __restrict__ enc,
    Res16 rt, DenseP dp, int p0, int P, int n_pts)
{
    int l = blockIdx.y;
    int tid = threadIdx.x;
    int sub = tid & 7;
    int ox = sub >> 2, oy = (sub >> 1) & 1, oz = sub & 1;
    int p = blockIdx.x * 32 + (tid >> 3);
    int pc = min(p, P - 1);
    int n = p0 + pc;

    // 8 lanes read the same 12B -> same-address merge, one lookup
    float px = (__builtin_nontemporal_load(&x[3*n+0]) + 1.f) * 0.5f;
    float py = (__builtin_nontemporal_load(&x[3*n+1]) + 1.f) * 0.5f;
    float pz = (__builtin_nontemporal_load(&x[3*n+2]) + 1.f) * 0.5f;

    float res = rt.r[l];
    float xs = px*res, ys = py*res, zs = pz*res;
    float fx = floorf(xs), fy = floorf(ys), fz = floorf(zs);
    float wx = xs - fx, wy = ys - fy, wz = zs - fz;
    float wgt = (ox ? wx : 1.f - wx) * (oy ? wy : 1.f - wy) * (oz ? wz : 1.f - wz);

    float f0, f1;
    if (l < NDL) {
        // dense path: corner's 4B within the z-pair entry
        int R = dp.R[l];
        int X = (int)fx + ox, Y = (int)fy + oy, Z = (int)fz;
        const u32* dl32 = (const u32*)(dense + dp.off[l]);
        u32 v = dl32[2 * ((X * R + Y) * R + Z) + oz];
        corner_vals(v, f0, f1);
    } else {
        // hash path
        unsigned X = (unsigned)fx + (unsigned)ox;
        unsigned Y = (unsigned)fy + (unsigned)oy;
        unsigned Z = (unsigned)fz + (unsigned)oz;
        unsigned idx = (X ^ (Y * 2654435761u) ^ (Z * 805459861u)) & (TBL_N - 1u);
        u32 v = tbl[(size_t)l * TBL_N + idx];
        corner_vals(v, f0, f1);
    }
    float e0 = wgt * f0, e1 = wgt * f1;
    e0 += __shfl_xor(e0, 1); e1 += __shfl_xor(e1, 1);
    e0 += __shfl_xor(e0, 2); e1 += __shfl_xor(e1, 2);
    e0 += __shfl_xor(e0, 4); e1 += __shfl_xor(e1, 4);

    if (sub == 0 && p < P)
        __builtin_nontemporal_store(pack_bf(e0, e1), &enc[(size_t)l * P + p]);
}

// ======================= Pack weights into MFMA A-fragments ================
__global__ __launch_bounds__(256) void nerf_pack_w(
    const float* __restrict__ sw0, const float* __restrict__ sb0,
    const float* __restrict__ sw1, const float* __restrict__ sb1,
    const float* __restrict__ cw0, const float* __restrict__ cb0,
    const float* __restrict__ cw1, const float* __restrict__ cb1,
    const float* __restrict__ cw2, const float* __restrict__ cb2,
    u16* __restrict__ wf, float* __restrict__ bi)
{
    int tid = threadIdx.x;
    for (int e = tid; e < 14336; e += 256) {
        int f = e >> 9, r = e & 511, lane = r >> 3, j = r & 7;
        int fo = lane & 15, G = lane >> 4;
        float val = 0.f;
        if (f < 4) {                       // L0: W = sw0^T, K=32
            int o = f*16 + fo, i = G*8 + j;
            val = sw0[i*64 + o];
        } else if (f < 6) {                // L1: K=64, M=16
            int o = fo, i = (f-4)*32 + G*8 + j;
            val = sw1[i*16 + o];
        } else if (f < 18) {               // C0: K=96 permuted
            int t = f - 6, mt = t / 3, kt = t % 3;
            int o = mt*16 + fo, i = kt*32 + G*8 + j;
            int row = (i < 16) ? (15 + i) : (i < 64) ? (31 + (i - 16)) : (i < 79) ? (i - 64) : -1;
            val = (row < 0) ? 0.f : cw0[row*64 + o];
        } else if (f < 26) {               // C1: K=64
            int t = f - 18, mt = t >> 1, kt = t & 1;
            int o = mt*16 + fo, i = kt*32 + G*8 + j;
            val = cw1[i*64 + o];
        } else {                           // C2: M=16 (3 real), K=64
            int kt = f - 26;
            int o = fo, i = kt*32 + G*8 + j;
            val = (o < 3) ? cw2[i*3 + o] : 0.f;
        }
        wf[e] = f2bf(val);
    }
    for (int i2 = tid; i2 < 224; i2 += 256) {
        float v;
        if (i2 < 64) v = sb0[i2];
        else if (i2 < 80) v = sb1[i2 - 64];
        else if (i2 < 144) v = cb0[i2 - 80];
        else if (i2 < 208) v = cb1[i2 - 144];
        else v = (i2 - 208 < 3) ? cb2[i2 - 208] : 0.f;
        bi[i2] = v;
    }
}

// ======================= Kernel M: MFMA MLP ================================
#define ASTRIDE 104   // ushorts per point row in ACT (>=96, 16B-multiple)

__global__ __launch_bounds__(256) void nerf_mlp_mfma(
    const u16* __restrict__ wfg, const float* __restrict__ big,
    const u32* __restrict__ enc,
    const float* __restrict__ dvec, const int* __restrict__ app_idx,
    const float* __restrict__ app_table,
    float* __restrict__ out, int p0, int P, int n_pts)
{
    __shared__ __align__(16) u16 WF[14336];
    __shared__ __align__(16) float BI[224];
    __shared__ __align__(16) u16 ACT[4][16 * ASTRIDE];

    int tid = threadIdx.x;
    int w = tid >> 6, l = tid & 63;
    int G = l >> 4, pq = l & 15;
    int pl = blockIdx.x * 64 + w * 16 + pq;
    int pc = min(pl, P - 1);
    int n = p0 + pc;

    uint4 ed;
    {
        const u32* encp = enc + pc;
        ed.x = __builtin_nontemporal_load(encp + (size_t)(4*G+0) * P);
        ed.y = __builtin_nontemporal_load(encp + (size_t)(4*G+1) * P);
        ed.z = __builtin_nontemporal_load(encp + (size_t)(4*G+2) * P);
        ed.w = __builtin_nontemporal_load(encp + (size_t)(4*G+3) * P);
    }
    s8v encf = __builtin_bit_cast(s8v, ed);
    float dx = __builtin_nontemporal_load(&dvec[3*n+0]);
    float dy = __builtin_nontemporal_load(&dvec[3*n+1]);
    float dz = __builtin_nontemporal_load(&dvec[3*n+2]);
    int ai = app_idx[n];
    const f4v* arow = (const f4v*)(app_table + (size_t)ai * 48 + 12 * G);
    f4v a0 = arow[0], a1 = arow[1], a2 = arow[2];

    for (int i = tid; i < 1792; i += 256) ((uint4*)WF)[i] = ((const uint4*)wfg)[i];
    for (int i = tid; i < 224; i += 256) BI[i] = big[i];
    if (G == 3) {
        ACT[w][pq*ASTRIDE + 79] = 0;
        #pragma unroll
        for (int k = 0; k < 8; k++) *(u32*)&ACT[w][pq*ASTRIDE + 80 + 2*k] = 0u;
    }
    __syncthreads();

    // ---- L0 ----
    f4v acc0[4];
    #pragma unroll
    for (int mt = 0; mt < 4; mt++) acc0[mt] = *(const f4v*)&BI[mt*16 + 4*G];
    #pragma unroll
    for (int mt = 0; mt < 4; mt++) {
        s8v wfr = *(const s8v*)&WF[mt*512 + l*8];
        acc0[mt] = __builtin_amdgcn_mfma_f32_16x16x32_bf16(wfr, encf, acc0[mt], 0, 0, 0);
    }
    #pragma unroll
    for (int mt = 0; mt < 4; mt++) {
        f4v v = acc0[mt];
        *(u32*)&ACT[w][pq*ASTRIDE + mt*16 + 4*G]     = pack_bf(fmaxf(v[0],0.f), fmaxf(v[1],0.f));
        *(u32*)&ACT[w][pq*ASTRIDE + mt*16 + 4*G + 2] = pack_bf(fmaxf(v[2],0.f), fmaxf(v[3],0.f));
    }

    // ---- L1 (raw) ----
    f4v acc1 = *(const f4v*)&BI[64 + 4*G];
    #pragma unroll
    for (int kt = 0; kt < 2; kt++) {
        s8v b = *(const s8v*)&ACT[w][pq*ASTRIDE + kt*32 + G*8];
        s8v wfr = *(const s8v*)&WF[(4+kt)*512 + l*8];
        acc1 = __builtin_amdgcn_mfma_f32_16x16x32_bf16(wfr, b, acc1, 0, 0, 0);
    }
    float sig_raw = acc1[0];

    // ---- C0 activation build ----
    {
        float invn = 1.0f / sqrtf(dx*dx + dy*dy + dz*dz);
        float ndx = dx*invn, ndy = dy*invn, ndz = dz*invn;
        float xx = ndx*ndx, yy = ndy*ndy, zz = ndz*ndz;
        float xy = ndx*ndy, yz = ndy*ndz, xz = ndx*ndz;
        float s0, s1, s2, s3;
        if (G == 0) {
            s0 =  0.28209479177387814f;
            s1 = -0.48860251190291987f * ndy;
            s2 =  0.48860251190291987f * ndz;
            s3 = -0.48860251190291987f * ndx;
        } else if (G == 1) {
            s0 =  1.0925484305920792f * xy;
            s1 = -1.0925484305920792f * yz;
            s2 =  0.94617469575756f * zz - 0.31539156525252005f;
            s3 = -1.0925484305920792f * xz;
        } else if (G == 2) {
            s0 =  0.5462742152960396f * (xx - yy);
            s1 = -0.5900435899266435f * ndy * (3.f*xx - yy);
            s2 =  2.890611442640554f * xy * ndz;
            s3 = -0.4570457994644657f * ndy * (4.f*zz - xx - yy);
        } else {
            s0 =  0.37317633259011546f * ndz * (2.f*zz - 3.f*xx - 3.f*yy);
            s1 = -0.4570457994644657f * ndx * (4.f*zz - xx - yy);
            s2 =  1.445305721320277f * ndz * (xx - yy);
            s3 = -0.5900435899266435f * ndx * (xx - 3.f*yy);
        }
        *(u32*)&ACT[w][pq*ASTRIDE + 4*G]     = pack_bf(s0, s1);
        *(u32*)&ACT[w][pq*ASTRIDE + 4*G + 2] = pack_bf(s2, s3);
        *(u32*)&ACT[w][pq*ASTRIDE + 16 + 12*G     ] = pack_bf(a0[0], a0[1]);
        *(u32*)&ACT[w][pq*ASTRIDE + 16 + 12*G + 2 ] = pack_bf(a0[2], a0[3]);
        *(u32*)&ACT[w][pq*ASTRIDE + 16 + 12*G + 4 ] = pack_bf(a1[0], a1[1]);
        *(u32*)&ACT[w][pq*ASTRIDE + 16 + 12*G + 6 ] = pack_bf(a1[2], a1[3]);
        *(u32*)&ACT[w][pq*ASTRIDE + 16 + 12*G + 8 ] = pack_bf(a2[0], a2[1]);
        *(u32*)&ACT[w][pq*ASTRIDE + 16 + 12*G + 10] = pack_bf(a2[2], a2[3]);
        #pragma unroll
        for (int r2 = 0; r2 < 4; r2++) {
            int fp = 4*G + r2;
            if (fp >= 1) ACT[w][pq*ASTRIDE + 63 + fp] = f2bf(acc1[r2]);
        }
    }

    // ---- C0 ----
    f4v acc[4];
    #pragma unroll
    for (int mt = 0; mt < 4; mt++) acc[mt] = *(const f4v*)&BI[80 + mt*16 + 4*G];
    #pragma unroll
    for (int kt = 0; kt < 3; kt++) {
        s8v b = *(const s8v*)&ACT[w][pq*ASTRIDE + kt*32 + G*8];
        #pragma unroll
        for (int mt = 0; mt < 4; mt++) {
            s8v wfr = *(const s8v*)&WF[(6 + mt*3 + kt)*512 + l*8];
            acc[mt] = __builtin_amdgcn_mfma_f32_16x16x32_bf16(wfr, b, acc[mt], 0, 0, 0);
        }
    }
    #pragma unroll
    for (int mt = 0; mt < 4; mt++) {
        f4v v = acc[mt];
        *(u32*)&ACT[w][pq*ASTRIDE + mt*16 + 4*G]     = pack_bf(fmaxf(v[0],0.f), fmaxf(v[1],0.f));
        *(u32*)&ACT[w][pq*ASTRIDE + mt*16 + 4*G + 2] = pack_bf(fmaxf(v[2],0.f), fmaxf(v[3],0.f));
    }

    // ---- C1 ----
    #pragma unroll
    for (int mt = 0; mt < 4; mt++) acc[mt] = *(const f4v*)&BI[144 + mt*16 + 4*G];
    #pragma unroll
    for (int kt = 0; kt < 2; kt++) {
        s8v b = *(const s8v*)&ACT[w][pq*ASTRIDE + kt*32 + G*8];
        #pragma unroll
        for (int mt = 0; mt < 4; mt++) {
            s8v wfr = *(const s8v*)&WF[(18 + mt*2 + kt)*512 + l*8];
            acc[mt] = __builtin_amdgcn_mfma_f32_16x16x32_bf16(wfr, b, acc[mt], 0, 0, 0);
        }
    }
    #pragma unroll
    for (int mt = 0; mt < 4; mt++) {
        f4v v = acc[mt];
        *(u32*)&ACT[w][pq*ASTRIDE + mt*16 + 4*G]     = pack_bf(fmaxf(v[0],0.f), fmaxf(v[1],0.f));
        *(u32*)&ACT[w][pq*ASTRIDE + mt*16 + 4*G + 2] = pack_bf(fmaxf(v[2],0.f), fmaxf(v[3],0.f));
    }

    // ---- C2 ----
    f4v acc2 = *(const f4v*)&BI[208 + 4*G];
    #pragma unroll
    for (int kt = 0; kt < 2; kt++) {
        s8v b = *(const s8v*)&ACT[w][pq*ASTRIDE + kt*32 + G*8];
        s8v wfr = *(const s8v*)&WF[(26+kt)*512 + l*8];
        acc2 = __builtin_amdgcn_mfma_f32_16x16x32_bf16(wfr, b, acc2, 0, 0, 0);
    }

    if (G == 0 && pl < P) {
        float z100 = 100.f * sig_raw;
        float sigma = (z100 > 20.f) ? sig_raw : (log1pf(expf(z100)) * 0.01f);
        f4v o4;
        o4[0] = sigma;
        o4[1] = 1.f/(1.f+expf(-acc2[0]));
        o4[2] = 1.f/(1.f+expf(-acc2[1]));
        o4[3] = 1.f/(1.f+expf(-acc2[2]));
        __builtin_nontemporal_store(o4, (f4v*)out + (size_t)(p0 + pl));
    }
}

// ======================= Fused fallback (ws too small) =====================
template <int USE_BF16>
__global__ __launch_bounds__(256) void nerf_fused(
    const float* __restrict__ x,
    const float* __restrict__ dvec,
    const int*   __restrict__ app_idx,
    const void*  __restrict__ tbl_raw,
    const float* __restrict__ app_table,
    const float* __restrict__ sw0, const float* __restrict__ sb0,
    const float* __restrict__ sw1, const float* __restrict__ sb1,
    const float* __restrict__ cw0, const float* __restrict__ cb0,
    const float* __restrict__ cw1, const float* __restrict__ cb1,
    const float* __restrict__ cw2, const float* __restrict__ cb2,
    float* __restrict__ out, Res16 rt, int n_pts)
{
    using CT = typename std::conditional<USE_BF16 != 0, unsigned, float2>::type;
    const CT* __restrict__ tbl = (const CT*)tbl_raw;

    int n = blockIdx.x * blockDim.x + threadIdx.x;
    if (n >= n_pts) return;

    float px = (x[3*n+0] + 1.f) * 0.5f;
    float py = (x[3*n+1] + 1.f) * 0.5f;
    float pz = (x[3*n+2] + 1.f) * 0.5f;

    float e[2*NL];
    #pragma unroll
    for (int l = 0; l < NL; l++) {
        float res = rt.r[l];
        float xs = px*res, ys = py*res, zs = pz*res;
        float fx = floorf(xs), fy = floorf(ys), fz = floorf(zs);
        float wx = xs - fx, wy = ys - fy, wz = zs - fz;
        float ax = 1.f - wx, ay = 1.f - wy, az = 1.f - wz;
        unsigned X = (unsigned)fx, Y = (unsigned)fy, Z = (unsigned)fz;
        unsigned hx0 = X,               hx1 = X + 1u;
        unsigned hy0 = Y * 2654435761u, hy1 = hy0 + 2654435761u;
        unsigned hz0 = Z * 805459861u,  hz1 = hz0 + 805459861u;
        const CT* base = tbl + (size_t)l * TBL_N;
        float e0 = 0.f, e1 = 0.f;
        #pragma unroll
        for (int c = 0; c < 8; c++) {
            unsigned idx = (((c & 4) ? hx1 : hx0) ^
                            ((c & 2) ? hy1 : hy0) ^
                            ((c & 1) ? hz1 : hz0)) & (TBL_N - 1u);
            CT v = base[idx];
            float f0, f1;
            corner_vals(v, f0, f1);
            float wgt = ((c & 4) ? wx : ax) * ((c & 2) ? wy : ay) * ((c & 1) ? wz : az);
            e0 += wgt * f0;
            e1 += wgt * f1;
        }
        e[2*l] = e0; e[2*l+1] = e1;
    }

    float h[HID];
    #pragma unroll
    for (int o = 0; o < HID; o++) h[o] = sb0[o];
    #pragma unroll
    for (int l = 0; l < NL; l++) {
        const float* r0 = sw0 + (2 * l) * HID;
        float e0 = e[2*l], e1 = e[2*l+1];
        #pragma unroll
        for (int o = 0; o < HID; o++) h[o] += e0 * r0[o] + e1 * r0[HID + o];
    }
    #pragma unroll
    for (int o = 0; o < HID; o++) h[o] = fmaxf(h[o], 0.f);

    float h1[16];
    #pragma unroll
    for (int o = 0; o < 16; o++) h1[o] = sb1[o];
    #pragma unroll
    for (int i = 0; i < HID; i++) {
        float v = h[i];
        const float* wr = sw1 + i * 16;
        #pragma unroll
        for (int o = 0; o < 16; o++) h1[o] += v * wr[o];
    }

    float z100 = 100.f * h1[0];
    float sigma = (z100 > 20.f) ? h1[0] : (log1pf(expf(z100)) * 0.01f);

    float dx = dvec[3*n+0], dy = dvec[3*n+1], dz = dvec[3*n+2];
    float invn = 1.0f / sqrtf(dx*dx + dy*dy + dz*dz);
    dx *= invn; dy *= invn; dz *= invn;
    float xx = dx*dx, yy = dy*dy, zz = dz*dz;
    float xy = dx*dy, yz = dy*dz, xz = dx*dz;
    float sh[16];
    sh[0]  = 0.28209479177387814f;
    sh[1]  = -0.48860251190291987f * dy;
    sh[2]  =  0.48860251190291987f * dz;
    sh[3]  = -0.48860251190291987f * dx;
    sh[4]  =  1.0925484305920792f * xy;
    sh[5]  = -1.0925484305920792f * yz;
    sh[6]  =  0.94617469575756f * zz - 0.31539156525252005f;
    sh[7]  = -1.0925484305920792f * xz;
    sh[8]  =  0.5462742152960396f * (xx - yy);
    sh[9]  = -0.5900435899266435f * dy * (3.f * xx - yy);
    sh[10] =  2.890611442640554f * xy * dz;
    sh[11] = -0.4570457994644657f * dy * (4.f * zz - xx - yy);
    sh[12] =  0.37317633259011546f * dz * (2.f * zz - 3.f * xx - 3.f * yy);
    sh[13] = -0.4570457994644657f * dx * (4.f * zz - xx - yy);
    sh[14] =  1.445305721320277f * dz * (xx - yy);
    sh[15] = -0.5900435899266435f * dx * (xx - 3.f * yy);

    float c1[HID];
    #pragma unroll
    for (int o = 0; o < HID; o++) c1[o] = cb0[o];
    #pragma unroll
    for (int i = 0; i < 15; i++) {
        float v = h1[i + 1];
        const float* wr = cw0 + i * HID;
        #pragma unroll
        for (int o = 0; o < HID; o++) c1[o] += v * wr[o];
    }
    #pragma unroll
    for (int i = 0; i < 16; i++) {
        float v = sh[i];
        const float* wr = cw0 + (15 + i) * HID;
        #pragma unroll
        for (int o = 0; o < HID; o++) c1[o] += v * wr[o];
    }
    {
        const float4* arow = reinterpret_cast<const float4*>(app_table + (size_t)app_idx[n] * 48);
        for (int j4 = 0; j4 < 12; j4++) {
            float4 v = arow[j4];
            const float* wr = cw0 + (31 + 4 * j4) * HID;
            #pragma unroll
            for (int o = 0; o < HID; o++) c1[o] += v.x * wr[o];
            #pragma unroll
            for (int o = 0; o < HID; o++) c1[o] += v.y * wr[HID + o];
            #pragma unroll
            for (int o = 0; o < HID; o++) c1[o] += v.z * wr[2 * HID + o];
            #pragma unroll
            for (int o = 0; o < HID; o++) c1[o] += v.w * wr[3 * HID + o];
        }
    }
    #pragma unroll
    for (int o = 0; o < HID; o++) c1[o] = fmaxf(c1[o], 0.f);

    float c2[HID];
    #pragma unroll
    for (int o = 0; o < HID; o++) c2[o] = cb1[o];
    #pragma unroll
    for (int i = 0; i < HID; i++) {
        float v = c1[i];
        const float* wr = cw1 + i * HID;
        #pragma unroll
        for (int o = 0; o < HID; o++) c2[o] += v * wr[o];
    }
    #pragma unroll
    for (int o = 0; o < HID; o++) c2[o] = fmaxf(c2[o], 0.f);

    float r = cb2[0], g = cb2[1], b = cb2[2];
    #pragma unroll
    for (int i = 0; i < HID; i++) {
        float v = c2[i];
        r += v * cw2[i * 3 + 0];
        g += v * cw2[i * 3 + 1];
        b += v * cw2[i * 3 + 2];
    }
    r = 1.f / (1.f + expf(-r));
    g = 1.f / (1.f + expf(-g));
    b = 1.f / (1.f + expf(-b));

    reinterpret_cast<float4*>(out)[n] = make_float4(sigma, r, g, b);
}

extern "C" void kernel_launch(void* const* d_in, const int* in_sizes, int n_in,
                              void* d_out, int out_size, void* d_ws, size_t ws_size,
                              hipStream_t stream) {
    const float* x         = (const float*)d_in[0];
    const float* dvec      = (const float*)d_in[1];
    const int*   app_idx   = (const int*)  d_in[2];
    const float* ht        = (const float*)d_in[3];
    const float* app_table = (const float*)d_in[4];
    const float* sw0 = (const float*)d_in[5];
    const float* sb0 = (const float*)d_in[6];
    const float* sw1 = (const float*)d_in[7];
    const float* sb1 = (const float*)d_in[8];
    const float* cw0 = (const float*)d_in[9];
    const float* cb0 = (const float*)d_in[10];
    const float* cw1 = (const float*)d_in[11];
    const float* cb1 = (const float*)d_in[12];
    const float* cw2 = (const float*)d_in[13];
    const float* cb2 = (const float*)d_in[14];

    int n_pts = in_sizes[0] / 3;

    Res16 rt;
    double bb = exp(log(2048.0 / 16.0) / 15.0);
    for (int l = 0; l < NL; l++) rt.r[l] = (float)floor(16.0 * pow(bb, (double)l));

    DenseP dp;
    {
        int acc = 0;
        for (int l = 0; l < NDL; l++) {
            dp.R[l] = (int)rt.r[l] + 1;
            dp.off[l] = acc;
            acc += dp.R[l] * dp.R[l] * dp.R[l];
        }
        dp.total = acc;
    }

    const size_t tbl_entries = (size_t)NL * TBL_N;
    const size_t tbl_bytes = tbl_entries * sizeof(unsigned);       // 32 MiB
    const size_t WFRAG_OFF = tbl_bytes;
    const size_t BIAS_OFF  = WFRAG_OFF + 14336 * 2;
    const size_t DENSE_OFF = (BIAS_OFF + 224 * 4 + 255) & ~(size_t)255;
    const size_t ENC_OFF   = (DENSE_OFF + (size_t)dp.total * 8 + 255) & ~(size_t)255;

    if (ws_size >= ENC_OFF + (4u << 20)) {
        int nent = (int)tbl_entries;
        hipLaunchKernelGGL(repack_bf16, dim3((nent + 255) / 256), dim3(256), 0, stream,
                           ht, (unsigned*)d_ws, nent);
        u16*   wfrag = (u16*)  ((char*)d_ws + WFRAG_OFF);
        float* biasb = (float*)((char*)d_ws + BIAS_OFF);
        uint2* dense = (uint2*)((char*)d_ws + DENSE_OFF);
        hipLaunchKernelGGL(nerf_pack_w, dim3(1), dim3(256), 0, stream,
                           sw0, sb0, sw1, sb1, cw0, cb0, cw1, cb1, cw2, cb2,
                           wfrag, biasb);
        hipLaunchKernelGGL(build_dense, dim3((dp.total + 255) / 256), dim3(256), 0, stream,
                           (const u32*)d_ws, dense, dp);

        size_t cap = (ws_size - ENC_OFF) / 64;   // 64 B per point
        if (cap > (size_t)n_pts) cap = (size_t)n_pts;
        cap &= ~(size_t)255;
        if (cap == 0) cap = 256;
        u32* enc = (u32*)((char*)d_ws + ENC_OFF);

        for (long p0 = 0; p0 < (long)n_pts; p0 += (long)cap) {
            int P = (int)(((long)n_pts - p0) < (long)cap ? ((long)n_pts - p0) : (long)cap);
            hipLaunchKernelGGL(nerf_encode, dim3((P + 31) / 32, NL), dim3(256), 0, stream,
                               x, (const unsigned*)d_ws, dense, enc, rt, dp, (int)p0, P, n_pts);
            hipLaunchKernelGGL(nerf_mlp_mfma, dim3((P + 63) / 64), dim3(256), 0, stream,
                               wfrag, biasb, enc,
                               dvec, app_idx, app_table,
                               (float*)d_out, (int)p0, P, n_pts);
        }
    } else if (ws_size >= tbl_bytes) {
        int nent = (int)tbl_entries;
        hipLaunchKernelGGL(repack_bf16, dim3((nent + 255) / 256), dim3(256), 0, stream,
                           ht, (unsigned*)d_ws, nent);
        dim3 g((n_pts + 255) / 256), blk(256);
        hipLaunchKernelGGL((nerf_fused<1>), g, blk, 0, stream,
                           x, dvec, app_idx, (const void*)d_ws, app_table,
                           sw0, sb0, sw1, sb1, cw0, cb0, cw1, cb1, cw2, cb2,
                           (float*)d_out, rt, n_pts);
    } else {
        dim3 g((n_pts + 255) / 256), blk(256);
        hipLaunchKernelGGL((nerf_fused<0>), g, blk, 0, stream,
                           x, dvec, app_idx, (const void*)ht, app_table,
                           sw0, sb0, sw1, sb1, cw0, cb0, cw1, cb1, cw2, cb2,
                           (float*)d_out, rt, n_pts);
    }
}

// Round 13
// 1005.168 us; speedup vs baseline: 1.1573x; 1.1573x over previous
//
#include <hip/hip_runtime.h>
#include <cmath>
#include <type_traits>

#define NL 16
#define TBL_N (1u << 19)
#define HID 64
#define NDL 6   // dense (coarse) levels

typedef float f4v __attribute__((ext_vector_type(4)));
typedef float f2v __attribute__((ext_vector_type(2)));
typedef short s8v __attribute__((ext_vector_type(8)));
typedef unsigned int u32;
typedef unsigned short u16;

struct Res16 { float r[NL]; };
struct DenseP { int R[NDL]; int off[NDL]; int total; };

__device__ __host__ __forceinline__ unsigned short f2bf(float f) {
    unsigned u = __builtin_bit_cast(unsigned, f);
    unsigned r = (u + 0x7FFFu + ((u >> 16) & 1u)) >> 16;   // RNE
    return (unsigned short)r;
}
__device__ __forceinline__ u32 pack_bf(float a, float b) {
    return (u32)f2bf(a) | ((u32)f2bf(b) << 16);
}
__device__ __forceinline__ void corner_vals(unsigned v, float& f0, float& f1) {
    f0 = __uint_as_float(v << 16);
    f1 = __uint_as_float(v & 0xffff0000u);
}
__device__ __forceinline__ void corner_vals(float2 v, float& f0, float& f1) {
    f0 = v.x; f1 = v.y;
}

__global__ __launch_bounds__(256) void repack_bf16(const float* __restrict__ src,
                                                   unsigned* __restrict__ dst, int n) {
    int i = blockIdx.x * blockDim.x + threadIdx.x;
    if (i >= n) return;
    f2v v = __builtin_nontemporal_load((const f2v*)src + i);
    dst[i] = pack_bf(v.x, v.y);
}

// ======================= Build dense z-pair tables for levels 0..5 =========
__global__ __launch_bounds__(256) void build_dense(
    const u32* __restrict__ tbl, uint2* __restrict__ dense, DenseP dp)
{
    int e = blockIdx.x * 256 + threadIdx.x;
    if (e >= dp.total) return;
    int l = 0;
    #pragma unroll
    for (int i = 1; i < NDL; i++) if (e >= dp.off[i]) l = i;
    int cell = e - dp.off[l];
    int R = dp.R[l];
    int Z = cell % R; int t = cell / R; int Y = t % R; int X = t / R;
    u32 hy = (u32)Y * 2654435761u;
    u32 hz0 = (u32)Z * 805459861u;
    u32 hz1 = hz0 + 805459861u;
    u32 i0 = ((u32)X ^ hy ^ hz0) & (TBL_N - 1u);
    u32 i1 = ((u32)X ^ hy ^ hz1) & (TBL_N - 1u);
    const u32* base = tbl + (size_t)l * TBL_N;
    dense[e] = make_uint2(base[i0], base[i1]);
}

// ======================= Kernel E: level-partitioned encode ================
// Thread per point (low VALU). Hash path exploits PRIME_x==1: for even X,
// idx(X+1) = idx(X)^1, so one aligned uint2 load serves BOTH X-corners.
// Odd-X lanes issue a second exec-masked pair load. 8 -> avg 6 L2 lookups.
__global__ __launch_bounds__(256) void nerf_encode(
    const float* __restrict__ x,
    const uint2* __restrict__ tbl2,      // pair view of bf16 hash table
    const uint2* __restrict__ dense,
    u32* __restrict__ enc,
    Res16 rt, DenseP dp, int p0, int P, int n_pts)
{
    int l = blockIdx.y;
    int tid = threadIdx.x;
    int p = blockIdx.x * 256 + tid;
    int pc = min(p, P - 1);
    int n = p0 + pc;

    float px = (__builtin_nontemporal_load(&x[3*n+0]) + 1.f) * 0.5f;
    float py = (__builtin_nontemporal_load(&x[3*n+1]) + 1.f) * 0.5f;
    float pz = (__builtin_nontemporal_load(&x[3*n+2]) + 1.f) * 0.5f;

    float res = rt.r[l];
    float xs = px*res, ys = py*res, zs = pz*res;
    float fx = floorf(xs), fy = floorf(ys), fz = floorf(zs);
    float wx = xs - fx, wy = ys - fy, wz = zs - fz;
    float ax = 1.f - wx, ay = 1.f - wy, az = 1.f - wz;

    float e0 = 0.f, e1 = 0.f;
    if (l < NDL) {
        // ---- dense path: 4 aligned 8B z-pair loads ----
        int R = dp.R[l];
        int X = (int)fx, Y = (int)fy, Z = (int)fz;
        const uint2* dl = dense + dp.off[l];
        int c00 = (X * R + Y) * R + Z;
        uint2 v00 = dl[c00];
        uint2 v01 = dl[c00 + R];
        uint2 v10 = dl[c00 + R * R];
        uint2 v11 = dl[c00 + R * R + R];
        float wxy00 = ax*ay, wxy01 = ax*wy, wxy10 = wx*ay, wxy11 = wx*wy;
        float f0, f1;
        corner_vals(v00.x, f0, f1); e0 += wxy00*az*f0; e1 += wxy00*az*f1;
        corner_vals(v00.y, f0, f1); e0 += wxy00*wz*f0; e1 += wxy00*wz*f1;
        corner_vals(v01.x, f0, f1); e0 += wxy01*az*f0; e1 += wxy01*az*f1;
        corner_vals(v01.y, f0, f1); e0 += wxy01*wz*f0; e1 += wxy01*wz*f1;
        corner_vals(v10.x, f0, f1); e0 += wxy10*az*f0; e1 += wxy10*az*f1;
        corner_vals(v10.y, f0, f1); e0 += wxy10*wz*f0; e1 += wxy10*wz*f1;
        corner_vals(v11.x, f0, f1); e0 += wxy11*az*f0; e1 += wxy11*az*f1;
        corner_vals(v11.y, f0, f1); e0 += wxy11*wz*f0; e1 += wxy11*wz*f1;
    } else {
        // ---- hash path with X-pair uint2 loads ----
        unsigned X = (unsigned)fx;
        unsigned Y = (unsigned)fy, Z = (unsigned)fz;
        unsigned hy0 = Y * 2654435761u, hy1 = hy0 + 2654435761u;
        unsigned hz0 = Z * 805459861u,  hz1 = hz0 + 805459861u;
        bool xodd = (X & 1u) != 0u;
        const uint2* b2 = tbl2 + (size_t)l * (TBL_N / 2);
        #pragma unroll
        for (int c = 0; c < 4; c++) {
            unsigned hyz = ((c & 2) ? hy1 : hy0) ^ ((c & 1) ? hz1 : hz0);
            float wyz = ((c & 2) ? wy : ay) * ((c & 1) ? wz : az);
            unsigned idxA = (X ^ hyz) & (TBL_N - 1u);
            uint2 vA = b2[idxA >> 1];
            u32 a = (idxA & 1u) ? vA.y : vA.x;   // corner X
            u32 b = (idxA & 1u) ? vA.x : vA.y;   // corner X+1 when X even
            if (xodd) {
                unsigned idxB = ((X + 1u) ^ hyz) & (TBL_N - 1u);
                uint2 vB = b2[idxB >> 1];
                b = (idxB & 1u) ? vB.y : vB.x;
            }
            float fa0, fa1, fb0, fb1;
            corner_vals(a, fa0, fa1);
            corner_vals(b, fb0, fb1);
            e0 += wyz * (ax * fa0 + wx * fb0);
            e1 += wyz * (ax * fa1 + wx * fb1);
        }
    }
    __builtin_nontemporal_store(pack_bf(e0, e1), &enc[(size_t)l * P + pc]);
}

// ======================= Pack weights into MFMA A-fragments ================
__global__ __launch_bounds__(256) void nerf_pack_w(
    const float* __restrict__ sw0, const float* __restrict__ sb0,
    const float* __restrict__ sw1, const float* __restrict__ sb1,
    const float* __restrict__ cw0, const float* __restrict__ cb0,
    const float* __restrict__ cw1, const float* __restrict__ cb1,
    const float* __restrict__ cw2, const float* __restrict__ cb2,
    u16* __restrict__ wf, float* __restrict__ bi)
{
    int tid = threadIdx.x;
    for (int e = tid; e < 14336; e += 256) {
        int f = e >> 9, r = e & 511, lane = r >> 3, j = r & 7;
        int fo = lane & 15, G = lane >> 4;
        float val = 0.f;
        if (f < 4) {                       // L0: W = sw0^T, K=32
            int o = f*16 + fo, i = G*8 + j;
            val = sw0[i*64 + o];
        } else if (f < 6) {                // L1: K=64, M=16
            int o = fo, i = (f-4)*32 + G*8 + j;
            val = sw1[i*16 + o];
        } else if (f < 18) {               // C0: K=96 permuted
            int t = f - 6, mt = t / 3, kt = t % 3;
            int o = mt*16 + fo, i = kt*32 + G*8 + j;
            int row = (i < 16) ? (15 + i) : (i < 64) ? (31 + (i - 16)) : (i < 79) ? (i - 64) : -1;
            val = (row < 0) ? 0.f : cw0[row*64 + o];
        } else if (f < 26) {               // C1: K=64
            int t = f - 18, mt = t >> 1, kt = t & 1;
            int o = mt*16 + fo, i = kt*32 + G*8 + j;
            val = cw1[i*64 + o];
        } else {                           // C2: M=16 (3 real), K=64
            int kt = f - 26;
            int o = fo, i = kt*32 + G*8 + j;
            val = (o < 3) ? cw2[i*3 + o] : 0.f;
        }
        wf[e] = f2bf(val);
    }
    for (int i2 = tid; i2 < 224; i2 += 256) {
        float v;
        if (i2 < 64) v = sb0[i2];
        else if (i2 < 80) v = sb1[i2 - 64];
        else if (i2 < 144) v = cb0[i2 - 80];
        else if (i2 < 208) v = cb1[i2 - 144];
        else v = (i2 - 208 < 3) ? cb2[i2 - 208] : 0.f;
        bi[i2] = v;
    }
}

// ======================= Kernel M: MFMA MLP ================================
#define ASTRIDE 104   // ushorts per point row in ACT (>=96, 16B-multiple)

__global__ __launch_bounds__(256) void nerf_mlp_mfma(
    const u16* __restrict__ wfg, const float* __restrict__ big,
    const u32* __restrict__ enc,
    const float* __restrict__ dvec, const int* __restrict__ app_idx,
    const float* __restrict__ app_table,
    float* __restrict__ out, int p0, int P, int n_pts)
{
    __shared__ __align__(16) u16 WF[14336];
    __shared__ __align__(16) float BI[224];
    __shared__ __align__(16) u16 ACT[4][16 * ASTRIDE];

    int tid = threadIdx.x;
    int w = tid >> 6, l = tid & 63;
    int G = l >> 4, pq = l & 15;
    int pl = blockIdx.x * 64 + w * 16 + pq;
    int pc = min(pl, P - 1);
    int n = p0 + pc;

    uint4 ed;
    {
        const u32* encp = enc + pc;
        ed.x = __builtin_nontemporal_load(encp + (size_t)(4*G+0) * P);
        ed.y = __builtin_nontemporal_load(encp + (size_t)(4*G+1) * P);
        ed.z = __builtin_nontemporal_load(encp + (size_t)(4*G+2) * P);
        ed.w = __builtin_nontemporal_load(encp + (size_t)(4*G+3) * P);
    }
    s8v encf = __builtin_bit_cast(s8v, ed);
    float dx = __builtin_nontemporal_load(&dvec[3*n+0]);
    float dy = __builtin_nontemporal_load(&dvec[3*n+1]);
    float dz = __builtin_nontemporal_load(&dvec[3*n+2]);
    int ai = app_idx[n];
    const f4v* arow = (const f4v*)(app_table + (size_t)ai * 48 + 12 * G);
    f4v a0 = arow[0], a1 = arow[1], a2 = arow[2];

    for (int i = tid; i < 1792; i += 256) ((uint4*)WF)[i] = ((const uint4*)wfg)[i];
    for (int i = tid; i < 224; i += 256) BI[i] = big[i];
    if (G == 3) {
        ACT[w][pq*ASTRIDE + 79] = 0;
        #pragma unroll
        for (int k = 0; k < 8; k++) *(u32*)&ACT[w][pq*ASTRIDE + 80 + 2*k] = 0u;
    }
    __syncthreads();

    // ---- L0 ----
    f4v acc0[4];
    #pragma unroll
    for (int mt = 0; mt < 4; mt++) acc0[mt] = *(const f4v*)&BI[mt*16 + 4*G];
    #pragma unroll
    for (int mt = 0; mt < 4; mt++) {
        s8v wfr = *(const s8v*)&WF[mt*512 + l*8];
        acc0[mt] = __builtin_amdgcn_mfma_f32_16x16x32_bf16(wfr, encf, acc0[mt], 0, 0, 0);
    }
    #pragma unroll
    for (int mt = 0; mt < 4; mt++) {
        f4v v = acc0[mt];
        *(u32*)&ACT[w][pq*ASTRIDE + mt*16 + 4*G]     = pack_bf(fmaxf(v[0],0.f), fmaxf(v[1],0.f));
        *(u32*)&ACT[w][pq*ASTRIDE + mt*16 + 4*G + 2] = pack_bf(fmaxf(v[2],0.f), fmaxf(v[3],0.f));
    }

    // ---- L1 (raw) ----
    f4v acc1 = *(const f4v*)&BI[64 + 4*G];
    #pragma unroll
    for (int kt = 0; kt < 2; kt++) {
        s8v b = *(const s8v*)&ACT[w][pq*ASTRIDE + kt*32 + G*8];
        s8v wfr = *(const s8v*)&WF[(4+kt)*512 + l*8];
        acc1 = __builtin_amdgcn_mfma_f32_16x16x32_bf16(wfr, b, acc1, 0, 0, 0);
    }
    float sig_raw = acc1[0];

    // ---- C0 activation build ----
    {
        float invn = 1.0f / sqrtf(dx*dx + dy*dy + dz*dz);
        float ndx = dx*invn, ndy = dy*invn, ndz = dz*invn;
        float xx = ndx*ndx, yy = ndy*ndy, zz = ndz*ndz;
        float xy = ndx*ndy, yz = ndy*ndz, xz = ndx*ndz;
        float s0, s1, s2, s3;
        if (G == 0) {
            s0 =  0.28209479177387814f;
            s1 = -0.48860251190291987f * ndy;
            s2 =  0.48860251190291987f * ndz;
            s3 = -0.48860251190291987f * ndx;
        } else if (G == 1) {
            s0 =  1.0925484305920792f * xy;
            s1 = -1.0925484305920792f * yz;
            s2 =  0.94617469575756f * zz - 0.31539156525252005f;
            s3 = -1.0925484305920792f * xz;
        } else if (G == 2) {
            s0 =  0.5462742152960396f * (xx - yy);
            s1 = -0.5900435899266435f * ndy * (3.f*xx - yy);
            s2 =  2.890611442640554f * xy * ndz;
            s3 = -0.4570457994644657f * ndy * (4.f*zz - xx - yy);
        } else {
            s0 =  0.37317633259011546f * ndz * (2.f*zz - 3.f*xx - 3.f*yy);
            s1 = -0.4570457994644657f * ndx * (4.f*zz - xx - yy);
            s2 =  1.445305721320277f * ndz * (xx - yy);
            s3 = -0.5900435899266435f * ndx * (xx - 3.f*yy);
        }
        *(u32*)&ACT[w][pq*ASTRIDE + 4*G]     = pack_bf(s0, s1);
        *(u32*)&ACT[w][pq*ASTRIDE + 4*G + 2] = pack_bf(s2, s3);
        *(u32*)&ACT[w][pq*ASTRIDE + 16 + 12*G     ] = pack_bf(a0[0], a0[1]);
        *(u32*)&ACT[w][pq*ASTRIDE + 16 + 12*G + 2 ] = pack_bf(a0[2], a0[3]);
        *(u32*)&ACT[w][pq*ASTRIDE + 16 + 12*G + 4 ] = pack_bf(a1[0], a1[1]);
        *(u32*)&ACT[w][pq*ASTRIDE + 16 + 12*G + 6 ] = pack_bf(a1[2], a1[3]);
        *(u32*)&ACT[w][pq*ASTRIDE + 16 + 12*G + 8 ] = pack_bf(a2[0], a2[1]);
        *(u32*)&ACT[w][pq*ASTRIDE + 16 + 12*G + 10] = pack_bf(a2[2], a2[3]);
        #pragma unroll
        for (int r2 = 0; r2 < 4; r2++) {
            int fp = 4*G + r2;
            if (fp >= 1) ACT[w][pq*ASTRIDE + 63 + fp] = f2bf(acc1[r2]);
        }
    }

    // ---- C0 ----
    f4v acc[4];
    #pragma unroll
    for (int mt = 0; mt < 4; mt++) acc[mt] = *(const f4v*)&BI[80 + mt*16 + 4*G];
    #pragma unroll
    for (int kt = 0; kt < 3; kt++) {
        s8v b = *(const s8v*)&ACT[w][pq*ASTRIDE + kt*32 + G*8];
        #pragma unroll
        for (int mt = 0; mt < 4; mt++) {
            s8v wfr = *(const s8v*)&WF[(6 + mt*3 + kt)*512 + l*8];
            acc[mt] = __builtin_amdgcn_mfma_f32_16x16x32_bf16(wfr, b, acc[mt], 0, 0, 0);
        }
    }
    #pragma unroll
    for (int mt = 0; mt < 4; mt++) {
        f4v v = acc[mt];
        *(u32*)&ACT[w][pq*ASTRIDE + mt*16 + 4*G]     = pack_bf(fmaxf(v[0],0.f), fmaxf(v[1],0.f));
        *(u32*)&ACT[w][pq*ASTRIDE + mt*16 + 4*G + 2] = pack_bf(fmaxf(v[2],0.f), fmaxf(v[3],0.f));
    }

    // ---- C1 ----
    #pragma unroll
    for (int mt = 0; mt < 4; mt++) acc[mt] = *(const f4v*)&BI[144 + mt*16 + 4*G];
    #pragma unroll
    for (int kt = 0; kt < 2; kt++) {
        s8v b = *(const s8v*)&ACT[w][pq*ASTRIDE + kt*32 + G*8];
        #pragma unroll
        for (int mt = 0; mt < 4; mt++) {
            s8v wfr = *(const s8v*)&WF[(18 + mt*2 + kt)*512 + l*8];
            acc[mt] = __builtin_amdgcn_mfma_f32_16x16x32_bf16(wfr, b, acc[mt], 0, 0, 0);
        }
    }
    #pragma unroll
    for (int mt = 0; mt < 4; mt++) {
        f4v v = acc[mt];
        *(u32*)&ACT[w][pq*ASTRIDE + mt*16 + 4*G]     = pack_bf(fmaxf(v[0],0.f), fmaxf(v[1],0.f));
        *(u32*)&ACT[w][pq*ASTRIDE + mt*16 + 4*G + 2] = pack_bf(fmaxf(v[2],0.f), fmaxf(v[3],0.f));
    }

    // ---- C2 ----
    f4v acc2 = *(const f4v*)&BI[208 + 4*G];
    #pragma unroll
    for (int kt = 0; kt < 2; kt++) {
        s8v b = *(const s8v*)&ACT[w][pq*ASTRIDE + kt*32 + G*8];
        s8v wfr = *(const s8v*)&WF[(26+kt)*512 + l*8];
        acc2 = __builtin_amdgcn_mfma_f32_16x16x32_bf16(wfr, b, acc2, 0, 0, 0);
    }

    if (G == 0 && pl < P) {
        float z100 = 100.f * sig_raw;
        float sigma = (z100 > 20.f) ? sig_raw : (log1pf(expf(z100)) * 0.01f);
        f4v o4;
        o4[0] = sigma;
        o4[1] = 1.f/(1.f+expf(-acc2[0]));
        o4[2] = 1.f/(1.f+expf(-acc2[1]));
        o4[3] = 1.f/(1.f+expf(-acc2[2]));
        __builtin_nontemporal_store(o4, (f4v*)out + (size_t)(p0 + pl));
    }
}

// ======================= Fused fallback (ws too small) =====================
template <int USE_BF16>
__global__ __launch_bounds__(256) void nerf_fused(
    const float* __restrict__ x,
    const float* __restrict__ dvec,
    const int*   __restrict__ app_idx,
    const void*  __restrict__ tbl_raw,
    const float* __restrict__ app_table,
    const float* __restrict__ sw0, const float* __restrict__ sb0,
    const float* __restrict__ sw1, const float* __restrict__ sb1,
    const float* __restrict__ cw0, const float* __restrict__ cb0,
    const float* __restrict__ cw1, const float* __restrict__ cb1,
    const float* __restrict__ cw2, const float* __restrict__ cb2,
    float* __restrict__ out, Res16 rt, int n_pts)
{
    using CT = typename std::conditional<USE_BF16 != 0, unsigned, float2>::type;
    const CT* __restrict__ tbl = (const CT*)tbl_raw;

    int n = blockIdx.x * blockDim.x + threadIdx.x;
    if (n >= n_pts) return;

    float px = (x[3*n+0] + 1.f) * 0.5f;
    float py = (x[3*n+1] + 1.f) * 0.5f;
    float pz = (x[3*n+2] + 1.f) * 0.5f;

    float e[2*NL];
    #pragma unroll
    for (int l = 0; l < NL; l++) {
        float res = rt.r[l];
        float xs = px*res, ys = py*res, zs = pz*res;
        float fx = floorf(xs), fy = floorf(ys), fz = floorf(zs);
        float wx = xs - fx, wy = ys - fy, wz = zs - fz;
        float ax = 1.f - wx, ay = 1.f - wy, az = 1.f - wz;
        unsigned X = (unsigned)fx, Y = (unsigned)fy, Z = (unsigned)fz;
        unsigned hx0 = X,               hx1 = X + 1u;
        unsigned hy0 = Y * 2654435761u, hy1 = hy0 + 2654435761u;
        unsigned hz0 = Z * 805459861u,  hz1 = hz0 + 805459861u;
        const CT* base = tbl + (size_t)l * TBL_N;
        float e0 = 0.f, e1 = 0.f;
        #pragma unroll
        for (int c = 0; c < 8; c++) {
            unsigned idx = (((c & 4) ? hx1 : hx0) ^
                            ((c & 2) ? hy1 : hy0) ^
                            ((c & 1) ? hz1 : hz0)) & (TBL_N - 1u);
            CT v = base[idx];
            float f0, f1;
            corner_vals(v, f0, f1);
            float wgt = ((c & 4) ? wx : ax) * ((c & 2) ? wy : ay) * ((c & 1) ? wz : az);
            e0 += wgt * f0;
            e1 += wgt * f1;
        }
        e[2*l] = e0; e[2*l+1] = e1;
    }

    float h[HID];
    #pragma unroll
    for (int o = 0; o < HID; o++) h[o] = sb0[o];
    #pragma unroll
    for (int l = 0; l < NL; l++) {
        const float* r0 = sw0 + (2 * l) * HID;
        float e0 = e[2*l], e1 = e[2*l+1];
        #pragma unroll
        for (int o = 0; o < HID; o++) h[o] += e0 * r0[o] + e1 * r0[HID + o];
    }
    #pragma unroll
    for (int o = 0; o < HID; o++) h[o] = fmaxf(h[o], 0.f);

    float h1[16];
    #pragma unroll
    for (int o = 0; o < 16; o++) h1[o] = sb1[o];
    #pragma unroll
    for (int i = 0; i < HID; i++) {
        float v = h[i];
        const float* wr = sw1 + i * 16;
        #pragma unroll
        for (int o = 0; o < 16; o++) h1[o] += v * wr[o];
    }

    float z100 = 100.f * h1[0];
    float sigma = (z100 > 20.f) ? h1[0] : (log1pf(expf(z100)) * 0.01f);

    float dx = dvec[3*n+0], dy = dvec[3*n+1], dz = dvec[3*n+2];
    float invn = 1.0f / sqrtf(dx*dx + dy*dy + dz*dz);
    dx *= invn; dy *= invn; dz *= invn;
    float xx = dx*dx, yy = dy*dy, zz = dz*dz;
    float xy = dx*dy, yz = dy*dz, xz = dx*dz;
    float sh[16];
    sh[0]  = 0.28209479177387814f;
    sh[1]  = -0.48860251190291987f * dy;
    sh[2]  =  0.48860251190291987f * dz;
    sh[3]  = -0.48860251190291987f * dx;
    sh[4]  =  1.0925484305920792f * xy;
    sh[5]  = -1.0925484305920792f * yz;
    sh[6]  =  0.94617469575756f * zz - 0.31539156525252005f;
    sh[7]  = -1.0925484305920792f * xz;
    sh[8]  =  0.5462742152960396f * (xx - yy);
    sh[9]  = -0.5900435899266435f * dy * (3.f * xx - yy);
    sh[10] =  2.890611442640554f * xy * dz;
    sh[11] = -0.4570457994644657f * dy * (4.f * zz - xx - yy);
    sh[12] =  0.37317633259011546f * dz * (2.f * zz - 3.f * xx - 3.f * yy);
    sh[13] = -0.4570457994644657f * dx * (4.f * zz - xx - yy);
    sh[14] =  1.445305721320277f * dz * (xx - yy);
    sh[15] = -0.5900435899266435f * dx * (xx - 3.f * yy);

    float c1[HID];
    #pragma unroll
    for (int o = 0; o < HID; o++) c1[o] = cb0[o];
    #pragma unroll
    for (int i = 0; i < 15; i++) {
        float v = h1[i + 1];
        const float* wr = cw0 + i * HID;
        #pragma unroll
        for (int o = 0; o < HID; o++) c1[o] += v * wr[o];
    }
    #pragma unroll
    for (int i = 0; i < 16; i++) {
        float v = sh[i];
        const float* wr = cw0 + (15 + i) * HID;
        #pragma unroll
        for (int o = 0; o < HID; o++) c1[o] += v * wr[o];
    }
    {
        const float4* arow = reinterpret_cast<const float4*>(app_table + (size_t)app_idx[n] * 48);
        for (int j4 = 0; j4 < 12; j4++) {
            float4 v = arow[j4];
            const float* wr = cw0 + (31 + 4 * j4) * HID;
            #pragma unroll
            for (int o = 0; o < HID; o++) c1[o] += v.x * wr[o];
            #pragma unroll
            for (int o = 0; o < HID; o++) c1[o] += v.y * wr[HID + o];
            #pragma unroll
            for (int o = 0; o < HID; o++) c1[o] += v.z * wr[2 * HID + o];
            #pragma unroll
            for (int o = 0; o < HID; o++) c1[o] += v.w * wr[3 * HID + o];
        }
    }
    #pragma unroll
    for (int o = 0; o < HID; o++) c1[o] = fmaxf(c1[o], 0.f);

    float c2[HID];
    #pragma unroll
    for (int o = 0; o < HID; o++) c2[o] = cb1[o];
    #pragma unroll
    for (int i = 0; i < HID; i++) {
        float v = c1[i];
        const float* wr = cw1 + i * HID;
        #pragma unroll
        for (int o = 0; o < HID; o++) c2[o] += v * wr[o];
    }
    #pragma unroll
    for (int o = 0; o < HID; o++) c2[o] = fmaxf(c2[o], 0.f);

    float r = cb2[0], g = cb2[1], b = cb2[2];
    #pragma unroll
    for (int i = 0; i < HID; i++) {
        float v = c2[i];
        r += v * cw2[i * 3 + 0];
        g += v * cw2[i * 3 + 1];
        b += v * cw2[i * 3 + 2];
    }
    r = 1.f / (1.f + expf(-r));
    g = 1.f / (1.f + expf(-g));
    b = 1.f / (1.f + expf(-b));

    reinterpret_cast<float4*>(out)[n] = make_float4(sigma, r, g, b);
}

extern "C" void kernel_launch(void* const* d_in, const int* in_sizes, int n_in,
                              void* d_out, int out_size, void* d_ws, size_t ws_size,
                              hipStream_t stream) {
    const float* x         = (const float*)d_in[0];
    const float* dvec      = (const float*)d_in[1];
    const int*   app_idx   = (const int*)  d_in[2];
    const float* ht        = (const float*)d_in[3];
    const float* app_table = (const float*)d_in[4];
    const float* sw0 = (const float*)d_in[5];
    const float* sb0 = (const float*)d_in[6];
    const float* sw1 = (const float*)d_in[7];
    const float* sb1 = (const float*)d_in[8];
    const float* cw0 = (const float*)d_in[9];
    const float* cb0 = (const float*)d_in[10];
    const float* cw1 = (const float*)d_in[11];
    const float* cb1 = (const float*)d_in[12];
    const float* cw2 = (const float*)d_in[13];
    const float* cb2 = (const float*)d_in[14];

    int n_pts = in_sizes[0] / 3;

    Res16 rt;
    double bb = exp(log(2048.0 / 16.0) / 15.0);
    for (int l = 0; l < NL; l++) rt.r[l] = (float)floor(16.0 * pow(bb, (double)l));

    DenseP dp;
    {
        int acc = 0;
        for (int l = 0; l < NDL; l++) {
            dp.R[l] = (int)rt.r[l] + 1;
            dp.off[l] = acc;
            acc += dp.R[l] * dp.R[l] * dp.R[l];
        }
        dp.total = acc;
    }

    const size_t tbl_entries = (size_t)NL * TBL_N;
    const size_t tbl_bytes = tbl_entries * sizeof(unsigned);       // 32 MiB
    const size_t WFRAG_OFF = tbl_bytes;
    const size_t BIAS_OFF  = WFRAG_OFF + 14336 * 2;
    const size_t DENSE_OFF = (BIAS_OFF + 224 * 4 + 255) & ~(size_t)255;
    const size_t ENC_OFF   = (DENSE_OFF + (size_t)dp.total * 8 + 255) & ~(size_t)255;

    if (ws_size >= ENC_OFF + (4u << 20)) {
        int nent = (int)tbl_entries;
        hipLaunchKernelGGL(repack_bf16, dim3((nent + 255) / 256), dim3(256), 0, stream,
                           ht, (unsigned*)d_ws, nent);
        u16*   wfrag = (u16*)  ((char*)d_ws + WFRAG_OFF);
        float* biasb = (float*)((char*)d_ws + BIAS_OFF);
        uint2* dense = (uint2*)((char*)d_ws + DENSE_OFF);
        hipLaunchKernelGGL(nerf_pack_w, dim3(1), dim3(256), 0, stream,
                           sw0, sb0, sw1, sb1, cw0, cb0, cw1, cb1, cw2, cb2,
                           wfrag, biasb);
        hipLaunchKernelGGL(build_dense, dim3((dp.total + 255) / 256), dim3(256), 0, stream,
                           (const u32*)d_ws, dense, dp);

        size_t cap = (ws_size - ENC_OFF) / 64;   // 64 B per point
        if (cap > (size_t)n_pts) cap = (size_t)n_pts;
        cap &= ~(size_t)255;
        if (cap == 0) cap = 256;
        u32* enc = (u32*)((char*)d_ws + ENC_OFF);

        for (long p0 = 0; p0 < (long)n_pts; p0 += (long)cap) {
            int P = (int)(((long)n_pts - p0) < (long)cap ? ((long)n_pts - p0) : (long)cap);
            hipLaunchKernelGGL(nerf_encode, dim3((P + 255) / 256, NL), dim3(256), 0, stream,
                               x, (const uint2*)d_ws, dense, enc, rt, dp, (int)p0, P, n_pts);
            hipLaunchKernelGGL(nerf_mlp_mfma, dim3((P + 63) / 64), dim3(256), 0, stream,
                               wfrag, biasb, enc,
                               dvec, app_idx, app_table,
                               (float*)d_out, (int)p0, P, n_pts);
        }
    } else if (ws_size >= tbl_bytes) {
        int nent = (int)tbl_entries;
        hipLaunchKernelGGL(repack_bf16, dim3((nent + 255) / 256), dim3(256), 0, stream,
                           ht, (unsigned*)d_ws, nent);
        dim3 g((n_pts + 255) / 256), blk(256);
        hipLaunchKernelGGL((nerf_fused<1>), g, blk, 0, stream,
                           x, dvec, app_idx, (const void*)d_ws, app_table,
                           sw0, sb0, sw1, sb1, cw0, cb0, cw1, cb1, cw2, cb2,
                           (float*)d_out, rt, n_pts);
    } else {
        dim3 g((n_pts + 255) / 256), blk(256);
        hipLaunchKernelGGL((nerf_fused<0>), g, blk, 0, stream,
                           x, dvec, app_idx, (const void*)ht, app_table,
                           sw0, sb0, sw1, sb1, cw0, cb0, cw1, cb1, cw2, cb2,
                           (float*)d_out, rt, n_pts);
    }
}

// Round 14
// 973.593 us; speedup vs baseline: 1.1949x; 1.0324x over previous
//
#include <hip/hip_runtime.h>
#include <cmath>
#include <type_traits>

#define NL 16
#define TBL_N (1u << 19)
#define HID 64
#define NDL 6   // dense (coarse) levels

typedef float f4v __attribute__((ext_vector_type(4)));
typedef float f2v __attribute__((ext_vector_type(2)));
typedef short s8v __attribute__((ext_vector_type(8)));
typedef unsigned int u32;
typedef unsigned short u16;

struct Res16 { float r[NL]; };
struct DenseP { int R[NDL]; int off[NDL]; int total; };

__device__ __host__ __forceinline__ unsigned short f2bf(float f) {
    unsigned u = __builtin_bit_cast(unsigned, f);
    unsigned r = (u + 0x7FFFu + ((u >> 16) & 1u)) >> 16;   // RNE
    return (unsigned short)r;
}
__device__ __forceinline__ u32 pack_bf(float a, float b) {
    return (u32)f2bf(a) | ((u32)f2bf(b) << 16);
}
__device__ __forceinline__ void corner_vals(unsigned v, float& f0, float& f1) {
    f0 = __uint_as_float(v << 16);
    f1 = __uint_as_float(v & 0xffff0000u);
}
__device__ __forceinline__ void corner_vals(float2 v, float& f0, float& f1) {
    f0 = v.x; f1 = v.y;
}

__global__ __launch_bounds__(256) void repack_bf16(const float* __restrict__ src,
                                                   unsigned* __restrict__ dst, int n) {
    int i = blockIdx.x * blockDim.x + threadIdx.x;
    if (i >= n) return;
    f2v v = __builtin_nontemporal_load((const f2v*)src + i);
    dst[i] = pack_bf(v.x, v.y);
}

// ======================= Position prepass: pack (px,py,pz) as float4 =======
__global__ __launch_bounds__(256) void pos_prep(
    const float* __restrict__ x, f4v* __restrict__ pos, int p0, int P, int n_pts)
{
    int p = blockIdx.x * 256 + threadIdx.x;
    if (p >= P) return;
    int n = p0 + p;
    f4v v;
    v.x = (__builtin_nontemporal_load(&x[3*n+0]) + 1.f) * 0.5f;
    v.y = (__builtin_nontemporal_load(&x[3*n+1]) + 1.f) * 0.5f;
    v.z = (__builtin_nontemporal_load(&x[3*n+2]) + 1.f) * 0.5f;
    v.w = 0.f;
    __builtin_nontemporal_store(v, &pos[p]);
}

// ======================= Build dense quad tables for levels 0..5 ===========
// dense4[cell(X,Y,Z)] = { h(X,Y,Z), h(X,Y,Z+1), h(X,Y+1,Z), h(X,Y+1,Z+1) }
__global__ __launch_bounds__(256) void build_dense4(
    const u32* __restrict__ tbl, uint4* __restrict__ dense, DenseP dp)
{
    int e = blockIdx.x * 256 + threadIdx.x;
    if (e >= dp.total) return;
    int l = 0;
    #pragma unroll
    for (int i = 1; i < NDL; i++) if (e >= dp.off[i]) l = i;
    int cell = e - dp.off[l];
    int R = dp.R[l];
    int Z = cell % R; int t = cell / R; int Y = t % R; int X = t / R;
    u32 hy0 = (u32)Y * 2654435761u, hy1 = hy0 + 2654435761u;
    u32 hz0 = (u32)Z * 805459861u,  hz1 = hz0 + 805459861u;
    const u32* base = tbl + (size_t)l * TBL_N;
    uint4 v;
    v.x = base[((u32)X ^ hy0 ^ hz0) & (TBL_N - 1u)];
    v.y = base[((u32)X ^ hy0 ^ hz1) & (TBL_N - 1u)];
    v.z = base[((u32)X ^ hy1 ^ hz0) & (TBL_N - 1u)];
    v.w = base[((u32)X ^ hy1 ^ hz1) & (TBL_N - 1u)];
    dense[e] = v;
}

// ======================= Kernel E: level-partitioned encode ================
// Dense path: 2x 16B quad loads (X, X+1). Hash path: X-pair uint2 loads.
// Position: single 16B packed load. enc is l-major.
__global__ __launch_bounds__(256) void nerf_encode(
    const f4v* __restrict__ pos,
    const uint2* __restrict__ tbl2,
    const uint4* __restrict__ dense,
    u32* __restrict__ enc,
    Res16 rt, DenseP dp, int P)
{
    int l = blockIdx.y;
    int tid = threadIdx.x;
    int p = blockIdx.x * 256 + tid;
    int pc = min(p, P - 1);

    f4v pv = __builtin_nontemporal_load(&pos[pc]);
    float px = pv.x, py = pv.y, pz = pv.z;

    float res = rt.r[l];
    float xs = px*res, ys = py*res, zs = pz*res;
    float fx = floorf(xs), fy = floorf(ys), fz = floorf(zs);
    float wx = xs - fx, wy = ys - fy, wz = zs - fz;
    float ax = 1.f - wx, ay = 1.f - wy, az = 1.f - wz;

    float e0 = 0.f, e1 = 0.f;
    if (l < NDL) {
        // ---- dense quad path: 2 aligned 16B loads ----
        int R = dp.R[l];
        int X = (int)fx, Y = (int)fy, Z = (int)fz;
        const uint4* dl = dense + dp.off[l];
        int c00 = (X * R + Y) * R + Z;
        uint4 v0 = dl[c00];             // X   : {y0z0,y0z1,y1z0,y1z1}
        uint4 v1 = dl[c00 + R * R];     // X+1
        float s00 = ay*az, s01 = ay*wz, s10 = wy*az, s11 = wy*wz;
        float f0, f1;
        corner_vals(v0.x, f0, f1); e0 += ax*s00*f0; e1 += ax*s00*f1;
        corner_vals(v0.y, f0, f1); e0 += ax*s01*f0; e1 += ax*s01*f1;
        corner_vals(v0.z, f0, f1); e0 += ax*s10*f0; e1 += ax*s10*f1;
        corner_vals(v0.w, f0, f1); e0 += ax*s11*f0; e1 += ax*s11*f1;
        corner_vals(v1.x, f0, f1); e0 += wx*s00*f0; e1 += wx*s00*f1;
        corner_vals(v1.y, f0, f1); e0 += wx*s01*f0; e1 += wx*s01*f1;
        corner_vals(v1.z, f0, f1); e0 += wx*s10*f0; e1 += wx*s10*f1;
        corner_vals(v1.w, f0, f1); e0 += wx*s11*f0; e1 += wx*s11*f1;
    } else {
        // ---- hash path with X-pair uint2 loads ----
        unsigned X = (unsigned)fx;
        unsigned Y = (unsigned)fy, Z = (unsigned)fz;
        unsigned hy0 = Y * 2654435761u, hy1 = hy0 + 2654435761u;
        unsigned hz0 = Z * 805459861u,  hz1 = hz0 + 805459861u;
        bool xodd = (X & 1u) != 0u;
        const uint2* b2 = tbl2 + (size_t)l * (TBL_N / 2);
        #pragma unroll
        for (int c = 0; c < 4; c++) {
            unsigned hyz = ((c & 2) ? hy1 : hy0) ^ ((c & 1) ? hz1 : hz0);
            float wyz = ((c & 2) ? wy : ay) * ((c & 1) ? wz : az);
            unsigned idxA = (X ^ hyz) & (TBL_N - 1u);
            uint2 vA = b2[idxA >> 1];
            u32 a = (idxA & 1u) ? vA.y : vA.x;   // corner X
            u32 b = (idxA & 1u) ? vA.x : vA.y;   // corner X+1 when X even
            if (xodd) {
                unsigned idxB = ((X + 1u) ^ hyz) & (TBL_N - 1u);
                uint2 vB = b2[idxB >> 1];
                b = (idxB & 1u) ? vB.y : vB.x;
            }
            float fa0, fa1, fb0, fb1;
            corner_vals(a, fa0, fa1);
            corner_vals(b, fb0, fb1);
            e0 += wyz * (ax * fa0 + wx * fb0);
            e1 += wyz * (ax * fa1 + wx * fb1);
        }
    }
    __builtin_nontemporal_store(pack_bf(e0, e1), &enc[(size_t)l * P + pc]);
}

// ======================= Pack weights into MFMA A-fragments ================
__global__ __launch_bounds__(256) void nerf_pack_w(
    const float* __restrict__ sw0, const float* __restrict__ sb0,
    const float* __restrict__ sw1, const float* __restrict__ sb1,
    const float* __restrict__ cw0, const float* __restrict__ cb0,
    const float* __restrict__ cw1, const float* __restrict__ cb1,
    const float* __restrict__ cw2, const float* __restrict__ cb2,
    u16* __restrict__ wf, float* __restrict__ bi)
{
    int tid = threadIdx.x;
    for (int e = tid; e < 14336; e += 256) {
        int f = e >> 9, r = e & 511, lane = r >> 3, j = r & 7;
        int fo = lane & 15, G = lane >> 4;
        float val = 0.f;
        if (f < 4) {                       // L0: W = sw0^T, K=32
            int o = f*16 + fo, i = G*8 + j;
            val = sw0[i*64 + o];
        } else if (f < 6) {                // L1: K=64, M=16
            int o = fo, i = (f-4)*32 + G*8 + j;
            val = sw1[i*16 + o];
        } else if (f < 18) {               // C0: K=96 permuted
            int t = f - 6, mt = t / 3, kt = t % 3;
            int o = mt*16 + fo, i = kt*32 + G*8 + j;
            int row = (i < 16) ? (15 + i) : (i < 64) ? (31 + (i - 16)) : (i < 79) ? (i - 64) : -1;
            val = (row < 0) ? 0.f : cw0[row*64 + o];
        } else if (f < 26) {               // C1: K=64
            int t = f - 18, mt = t >> 1, kt = t & 1;
            int o = mt*16 + fo, i = kt*32 + G*8 + j;
            val = cw1[i*64 + o];
        } else {                           // C2: M=16 (3 real), K=64
            int kt = f - 26;
            int o = fo, i = kt*32 + G*8 + j;
            val = (o < 3) ? cw2[i*3 + o] : 0.f;
        }
        wf[e] = f2bf(val);
    }
    for (int i2 = tid; i2 < 224; i2 += 256) {
        float v;
        if (i2 < 64) v = sb0[i2];
        else if (i2 < 80) v = sb1[i2 - 64];
        else if (i2 < 144) v = cb0[i2 - 80];
        else if (i2 < 208) v = cb1[i2 - 144];
        else v = (i2 - 208 < 3) ? cb2[i2 - 208] : 0.f;
        bi[i2] = v;
    }
}

// ======================= Kernel M: MFMA MLP ================================
#define ASTRIDE 104   // ushorts per point row in ACT (>=96, 16B-multiple)

__global__ __launch_bounds__(256) void nerf_mlp_mfma(
    const u16* __restrict__ wfg, const float* __restrict__ big,
    const u32* __restrict__ enc,
    const float* __restrict__ dvec, const int* __restrict__ app_idx,
    const float* __restrict__ app_table,
    float* __restrict__ out, int p0, int P, int n_pts)
{
    __shared__ __align__(16) u16 WF[14336];
    __shared__ __align__(16) float BI[224];
    __shared__ __align__(16) u16 ACT[4][16 * ASTRIDE];

    int tid = threadIdx.x;
    int w = tid >> 6, l = tid & 63;
    int G = l >> 4, pq = l & 15;
    int pl = blockIdx.x * 64 + w * 16 + pq;
    int pc = min(pl, P - 1);
    int n = p0 + pc;

    uint4 ed;
    {
        const u32* encp = enc + pc;
        ed.x = __builtin_nontemporal_load(encp + (size_t)(4*G+0) * P);
        ed.y = __builtin_nontemporal_load(encp + (size_t)(4*G+1) * P);
        ed.z = __builtin_nontemporal_load(encp + (size_t)(4*G+2) * P);
        ed.w = __builtin_nontemporal_load(encp + (size_t)(4*G+3) * P);
    }
    s8v encf = __builtin_bit_cast(s8v, ed);
    float dx = __builtin_nontemporal_load(&dvec[3*n+0]);
    float dy = __builtin_nontemporal_load(&dvec[3*n+1]);
    float dz = __builtin_nontemporal_load(&dvec[3*n+2]);
    int ai = app_idx[n];
    const f4v* arow = (const f4v*)(app_table + (size_t)ai * 48 + 12 * G);
    f4v a0 = arow[0], a1 = arow[1], a2 = arow[2];

    for (int i = tid; i < 1792; i += 256) ((uint4*)WF)[i] = ((const uint4*)wfg)[i];
    for (int i = tid; i < 224; i += 256) BI[i] = big[i];
    if (G == 3) {
        ACT[w][pq*ASTRIDE + 79] = 0;
        #pragma unroll
        for (int k = 0; k < 8; k++) *(u32*)&ACT[w][pq*ASTRIDE + 80 + 2*k] = 0u;
    }
    __syncthreads();

    // ---- L0 ----
    f4v acc0[4];
    #pragma unroll
    for (int mt = 0; mt < 4; mt++) acc0[mt] = *(const f4v*)&BI[mt*16 + 4*G];
    #pragma unroll
    for (int mt = 0; mt < 4; mt++) {
        s8v wfr = *(const s8v*)&WF[mt*512 + l*8];
        acc0[mt] = __builtin_amdgcn_mfma_f32_16x16x32_bf16(wfr, encf, acc0[mt], 0, 0, 0);
    }
    #pragma unroll
    for (int mt = 0; mt < 4; mt++) {
        f4v v = acc0[mt];
        *(u32*)&ACT[w][pq*ASTRIDE + mt*16 + 4*G]     = pack_bf(fmaxf(v[0],0.f), fmaxf(v[1],0.f));
        *(u32*)&ACT[w][pq*ASTRIDE + mt*16 + 4*G + 2] = pack_bf(fmaxf(v[2],0.f), fmaxf(v[3],0.f));
    }

    // ---- L1 (raw) ----
    f4v acc1 = *(const f4v*)&BI[64 + 4*G];
    #pragma unroll
    for (int kt = 0; kt < 2; kt++) {
        s8v b = *(const s8v*)&ACT[w][pq*ASTRIDE + kt*32 + G*8];
        s8v wfr = *(const s8v*)&WF[(4+kt)*512 + l*8];
        acc1 = __builtin_amdgcn_mfma_f32_16x16x32_bf16(wfr, b, acc1, 0, 0, 0);
    }
    float sig_raw = acc1[0];

    // ---- C0 activation build ----
    {
        float invn = 1.0f / sqrtf(dx*dx + dy*dy + dz*dz);
        float ndx = dx*invn, ndy = dy*invn, ndz = dz*invn;
        float xx = ndx*ndx, yy = ndy*ndy, zz = ndz*ndz;
        float xy = ndx*ndy, yz = ndy*ndz, xz = ndx*ndz;
        float s0, s1, s2, s3;
        if (G == 0) {
            s0 =  0.28209479177387814f;
            s1 = -0.48860251190291987f * ndy;
            s2 =  0.48860251190291987f * ndz;
            s3 = -0.48860251190291987f * ndx;
        } else if (G == 1) {
            s0 =  1.0925484305920792f * xy;
            s1 = -1.0925484305920792f * yz;
            s2 =  0.94617469575756f * zz - 0.31539156525252005f;
            s3 = -1.0925484305920792f * xz;
        } else if (G == 2) {
            s0 =  0.5462742152960396f * (xx - yy);
            s1 = -0.5900435899266435f * ndy * (3.f*xx - yy);
            s2 =  2.890611442640554f * xy * ndz;
            s3 = -0.4570457994644657f * ndy * (4.f*zz - xx - yy);
        } else {
            s0 =  0.37317633259011546f * ndz * (2.f*zz - 3.f*xx - 3.f*yy);
            s1 = -0.4570457994644657f * ndx * (4.f*zz - xx - yy);
            s2 =  1.445305721320277f * ndz * (xx - yy);
            s3 = -0.5900435899266435f * ndx * (xx - 3.f*yy);
        }
        *(u32*)&ACT[w][pq*ASTRIDE + 4*G]     = pack_bf(s0, s1);
        *(u32*)&ACT[w][pq*ASTRIDE + 4*G + 2] = pack_bf(s2, s3);
        *(u32*)&ACT[w][pq*ASTRIDE + 16 + 12*G     ] = pack_bf(a0[0], a0[1]);
        *(u32*)&ACT[w][pq*ASTRIDE + 16 + 12*G + 2 ] = pack_bf(a0[2], a0[3]);
        *(u32*)&ACT[w][pq*ASTRIDE + 16 + 12*G + 4 ] = pack_bf(a1[0], a1[1]);
        *(u32*)&ACT[w][pq*ASTRIDE + 16 + 12*G + 6 ] = pack_bf(a1[2], a1[3]);
        *(u32*)&ACT[w][pq*ASTRIDE + 16 + 12*G + 8 ] = pack_bf(a2[0], a2[1]);
        *(u32*)&ACT[w][pq*ASTRIDE + 16 + 12*G + 10] = pack_bf(a2[2], a2[3]);
        #pragma unroll
        for (int r2 = 0; r2 < 4; r2++) {
            int fp = 4*G + r2;
            if (fp >= 1) ACT[w][pq*ASTRIDE + 63 + fp] = f2bf(acc1[r2]);
        }
    }

    // ---- C0 ----
    f4v acc[4];
    #pragma unroll
    for (int mt = 0; mt < 4; mt++) acc[mt] = *(const f4v*)&BI[80 + mt*16 + 4*G];
    #pragma unroll
    for (int kt = 0; kt < 3; kt++) {
        s8v b = *(const s8v*)&ACT[w][pq*ASTRIDE + kt*32 + G*8];
        #pragma unroll
        for (int mt = 0; mt < 4; mt++) {
            s8v wfr = *(const s8v*)&WF[(6 + mt*3 + kt)*512 + l*8];
            acc[mt] = __builtin_amdgcn_mfma_f32_16x16x32_bf16(wfr, b, acc[mt], 0, 0, 0);
        }
    }
    #pragma unroll
    for (int mt = 0; mt < 4; mt++) {
        f4v v = acc[mt];
        *(u32*)&ACT[w][pq*ASTRIDE + mt*16 + 4*G]     = pack_bf(fmaxf(v[0],0.f), fmaxf(v[1],0.f));
        *(u32*)&ACT[w][pq*ASTRIDE + mt*16 + 4*G + 2] = pack_bf(fmaxf(v[2],0.f), fmaxf(v[3],0.f));
    }

    // ---- C1 ----
    #pragma unroll
    for (int mt = 0; mt < 4; mt++) acc[mt] = *(const f4v*)&BI[144 + mt*16 + 4*G];
    #pragma unroll
    for (int kt = 0; kt < 2; kt++) {
        s8v b = *(const s8v*)&ACT[w][pq*ASTRIDE + kt*32 + G*8];
        #pragma unroll
        for (int mt = 0; mt < 4; mt++) {
            s8v wfr = *(const s8v*)&WF[(18 + mt*2 + kt)*512 + l*8];
            acc[mt] = __builtin_amdgcn_mfma_f32_16x16x32_bf16(wfr, b, acc[mt], 0, 0, 0);
        }
    }
    #pragma unroll
    for (int mt = 0; mt < 4; mt++) {
        f4v v = acc[mt];
        *(u32*)&ACT[w][pq*ASTRIDE + mt*16 + 4*G]     = pack_bf(fmaxf(v[0],0.f), fmaxf(v[1],0.f));
        *(u32*)&ACT[w][pq*ASTRIDE + mt*16 + 4*G + 2] = pack_bf(fmaxf(v[2],0.f), fmaxf(v[3],0.f));
    }

    // ---- C2 ----
    f4v acc2 = *(const f4v*)&BI[208 + 4*G];
    #pragma unroll
    for (int kt = 0; kt < 2; kt++) {
        s8v b = *(const s8v*)&ACT[w][pq*ASTRIDE + kt*32 + G*8];
        s8v wfr = *(const s8v*)&WF[(26+kt)*512 + l*8];
        acc2 = __builtin_amdgcn_mfma_f32_16x16x32_bf16(wfr, b, acc2, 0, 0, 0);
    }

    if (G == 0 && pl < P) {
        float z100 = 100.f * sig_raw;
        float sigma = (z100 > 20.f) ? sig_raw : (log1pf(expf(z100)) * 0.01f);
        f4v o4;
        o4[0] = sigma;
        o4[1] = 1.f/(1.f+expf(-acc2[0]));
        o4[2] = 1.f/(1.f+expf(-acc2[1]));
        o4[3] = 1.f/(1.f+expf(-acc2[2]));
        __builtin_nontemporal_store(o4, (f4v*)out + (size_t)(p0 + pl));
    }
}

// ======================= Fused fallback (ws too small) =====================
template <int USE_BF16>
__global__ __launch_bounds__(256) void nerf_fused(
    const float* __restrict__ x,
    const float* __restrict__ dvec,
    const int*   __restrict__ app_idx,
    const void*  __restrict__ tbl_raw,
    const float* __restrict__ app_table,
    const float* __restrict__ sw0, const float* __restrict__ sb0,
    const float* __restrict__ sw1, const float* __restrict__ sb1,
    const float* __restrict__ cw0, const float* __restrict__ cb0,
    const float* __restrict__ cw1, const float* __restrict__ cb1,
    const float* __restrict__ cw2, const float* __restrict__ cb2,
    float* __restrict__ out, Res16 rt, int n_pts)
{
    using CT = typename std::conditional<USE_BF16 != 0, unsigned, float2>::type;
    const CT* __restrict__ tbl = (const CT*)tbl_raw;

    int n = blockIdx.x * blockDim.x + threadIdx.x;
    if (n >= n_pts) return;

    float px = (x[3*n+0] + 1.f) * 0.5f;
    float py = (x[3*n+1] + 1.f) * 0.5f;
    float pz = (x[3*n+2] + 1.f) * 0.5f;

    float e[2*NL];
    #pragma unroll
    for (int l = 0; l < NL; l++) {
        float res = rt.r[l];
        float xs = px*res, ys = py*res, zs = pz*res;
        float fx = floorf(xs), fy = floorf(ys), fz = floorf(zs);
        float wx = xs - fx, wy = ys - fy, wz = zs - fz;
        float ax = 1.f - wx, ay = 1.f - wy, az = 1.f - wz;
        unsigned X = (unsigned)fx, Y = (unsigned)fy, Z = (unsigned)fz;
        unsigned hx0 = X,               hx1 = X + 1u;
        unsigned hy0 = Y * 2654435761u, hy1 = hy0 + 2654435761u;
        unsigned hz0 = Z * 805459861u,  hz1 = hz0 + 805459861u;
        const CT* base = tbl + (size_t)l * TBL_N;
        float e0 = 0.f, e1 = 0.f;
        #pragma unroll
        for (int c = 0; c < 8; c++) {
            unsigned idx = (((c & 4) ? hx1 : hx0) ^
                            ((c & 2) ? hy1 : hy0) ^
                            ((c & 1) ? hz1 : hz0)) & (TBL_N - 1u);
            CT v = base[idx];
            float f0, f1;
            corner_vals(v, f0, f1);
            float wgt = ((c & 4) ? wx : ax) * ((c & 2) ? wy : ay) * ((c & 1) ? wz : az);
            e0 += wgt * f0;
            e1 += wgt * f1;
        }
        e[2*l] = e0; e[2*l+1] = e1;
    }

    float h[HID];
    #pragma unroll
    for (int o = 0; o < HID; o++) h[o] = sb0[o];
    #pragma unroll
    for (int l = 0; l < NL; l++) {
        const float* r0 = sw0 + (2 * l) * HID;
        float e0 = e[2*l], e1 = e[2*l+1];
        #pragma unroll
        for (int o = 0; o < HID; o++) h[o] += e0 * r0[o] + e1 * r0[HID + o];
    }
    #pragma unroll
    for (int o = 0; o < HID; o++) h[o] = fmaxf(h[o], 0.f);

    float h1[16];
    #pragma unroll
    for (int o = 0; o < 16; o++) h1[o] = sb1[o];
    #pragma unroll
    for (int i = 0; i < HID; i++) {
        float v = h[i];
        const float* wr = sw1 + i * 16;
        #pragma unroll
        for (int o = 0; o < 16; o++) h1[o] += v * wr[o];
    }

    float z100 = 100.f * h1[0];
    float sigma = (z100 > 20.f) ? h1[0] : (log1pf(expf(z100)) * 0.01f);

    float dx = dvec[3*n+0], dy = dvec[3*n+1], dz = dvec[3*n+2];
    float invn = 1.0f / sqrtf(dx*dx + dy*dy + dz*dz);
    dx *= invn; dy *= invn; dz *= invn;
    float xx = dx*dx, yy = dy*dy, zz = dz*dz;
    float xy = dx*dy, yz = dy*dz, xz = dx*dz;
    float sh[16];
    sh[0]  = 0.28209479177387814f;
    sh[1]  = -0.48860251190291987f * dy;
    sh[2]  =  0.48860251190291987f * dz;
    sh[3]  = -0.48860251190291987f * dx;
    sh[4]  =  1.0925484305920792f * xy;
    sh[5]  = -1.0925484305920792f * yz;
    sh[6]  =  0.94617469575756f * zz - 0.31539156525252005f;
    sh[7]  = -1.0925484305920792f * xz;
    sh[8]  =  0.5462742152960396f * (xx - yy);
    sh[9]  = -0.5900435899266435f * dy * (3.f * xx - yy);
    sh[10] =  2.890611442640554f * xy * dz;
    sh[11] = -0.4570457994644657f * dy * (4.f * zz - xx - yy);
    sh[12] =  0.37317633259011546f * dz * (2.f * zz - 3.f * xx - 3.f * yy);
    sh[13] = -0.4570457994644657f * dx * (4.f * zz - xx - yy);
    sh[14] =  1.445305721320277f * dz * (xx - yy);
    sh[15] = -0.5900435899266435f * dx * (xx - 3.f * yy);

    float c1[HID];
    #pragma unroll
    for (int o = 0; o < HID; o++) c1[o] = cb0[o];
    #pragma unroll
    for (int i = 0; i < 15; i++) {
        float v = h1[i + 1];
        const float* wr = cw0 + i * HID;
        #pragma unroll
        for (int o = 0; o < HID; o++) c1[o] += v * wr[o];
    }
    #pragma unroll
    for (int i = 0; i < 16; i++) {
        float v = sh[i];
        const float* wr = cw0 + (15 + i) * HID;
        #pragma unroll
        for (int o = 0; o < HID; o++) c1[o] += v * wr[o];
    }
    {
        const float4* arow = reinterpret_cast<const float4*>(app_table + (size_t)app_idx[n] * 48);
        for (int j4 = 0; j4 < 12; j4++) {
            float4 v = arow[j4];
            const float* wr = cw0 + (31 + 4 * j4) * HID;
            #pragma unroll
            for (int o = 0; o < HID; o++) c1[o] += v.x * wr[o];
            #pragma unroll
            for (int o = 0; o < HID; o++) c1[o] += v.y * wr[HID + o];
            #pragma unroll
            for (int o = 0; o < HID; o++) c1[o] += v.z * wr[2 * HID + o];
            #pragma unroll
            for (int o = 0; o < HID; o++) c1[o] += v.w * wr[3 * HID + o];
        }
    }
    #pragma unroll
    for (int o = 0; o < HID; o++) c1[o] = fmaxf(c1[o], 0.f);

    float c2[HID];
    #pragma unroll
    for (int o = 0; o < HID; o++) c2[o] = cb1[o];
    #pragma unroll
    for (int i = 0; i < HID; i++) {
        float v = c1[i];
        const float* wr = cw1 + i * HID;
        #pragma unroll
        for (int o = 0; o < HID; o++) c2[o] += v * wr[o];
    }
    #pragma unroll
    for (int o = 0; o < HID; o++) c2[o] = fmaxf(c2[o], 0.f);

    float r = cb2[0], g = cb2[1], b = cb2[2];
    #pragma unroll
    for (int i = 0; i < HID; i++) {
        float v = c2[i];
        r += v * cw2[i * 3 + 0];
        g += v * cw2[i * 3 + 1];
        b += v * cw2[i * 3 + 2];
    }
    r = 1.f / (1.f + expf(-r));
    g = 1.f / (1.f + expf(-g));
    b = 1.f / (1.f + expf(-b));

    reinterpret_cast<float4*>(out)[n] = make_float4(sigma, r, g, b);
}

extern "C" void kernel_launch(void* const* d_in, const int* in_sizes, int n_in,
                              void* d_out, int out_size, void* d_ws, size_t ws_size,
                              hipStream_t stream) {
    const float* x         = (const float*)d_in[0];
    const float* dvec      = (const float*)d_in[1];
    const int*   app_idx   = (const int*)  d_in[2];
    const float* ht        = (const float*)d_in[3];
    const float* app_table = (const float*)d_in[4];
    const float* sw0 = (const float*)d_in[5];
    const float* sb0 = (const float*)d_in[6];
    const float* sw1 = (const float*)d_in[7];
    const float* sb1 = (const float*)d_in[8];
    const float* cw0 = (const float*)d_in[9];
    const float* cb0 = (const float*)d_in[10];
    const float* cw1 = (const float*)d_in[11];
    const float* cb1 = (const float*)d_in[12];
    const float* cw2 = (const float*)d_in[13];
    const float* cb2 = (const float*)d_in[14];

    int n_pts = in_sizes[0] / 3;

    Res16 rt;
    double bb = exp(log(2048.0 / 16.0) / 15.0);
    for (int l = 0; l < NL; l++) rt.r[l] = (float)floor(16.0 * pow(bb, (double)l));

    DenseP dp;
    {
        int acc = 0;
        for (int l = 0; l < NDL; l++) {
            dp.R[l] = (int)rt.r[l] + 1;
            dp.off[l] = acc;
            acc += dp.R[l] * dp.R[l] * dp.R[l];
        }
        dp.total = acc;
    }

    const size_t tbl_entries = (size_t)NL * TBL_N;
    const size_t tbl_bytes = tbl_entries * sizeof(unsigned);       // 32 MiB
    const size_t WFRAG_OFF = tbl_bytes;
    const size_t BIAS_OFF  = WFRAG_OFF + 14336 * 2;
    const size_t DENSE_OFF = (BIAS_OFF + 224 * 4 + 255) & ~(size_t)255;
    const size_t CHUNK_OFF = (DENSE_OFF + (size_t)dp.total * 16 + 255) & ~(size_t)255;

    if (ws_size >= CHUNK_OFF + (8u << 20)) {
        int nent = (int)tbl_entries;
        hipLaunchKernelGGL(repack_bf16, dim3((nent + 255) / 256), dim3(256), 0, stream,
                           ht, (unsigned*)d_ws, nent);
        u16*   wfrag = (u16*)  ((char*)d_ws + WFRAG_OFF);
        float* biasb = (float*)((char*)d_ws + BIAS_OFF);
        uint4* dense = (uint4*)((char*)d_ws + DENSE_OFF);
        hipLaunchKernelGGL(nerf_pack_w, dim3(1), dim3(256), 0, stream,
                           sw0, sb0, sw1, sb1, cw0, cb0, cw1, cb1, cw2, cb2,
                           wfrag, biasb);
        hipLaunchKernelGGL(build_dense4, dim3((dp.total + 255) / 256), dim3(256), 0, stream,
                           (const u32*)d_ws, dense, dp);

        // chunk region: pos (16 B/pt) + enc (64 B/pt) = 80 B/pt
        size_t cap = (ws_size - CHUNK_OFF) / 80;
        if (cap > (size_t)n_pts) cap = (size_t)n_pts;
        cap &= ~(size_t)255;
        if (cap == 0) cap = 256;
        f4v* pos = (f4v*)((char*)d_ws + CHUNK_OFF);
        u32* enc = (u32*)((char*)d_ws + CHUNK_OFF + cap * 16);

        for (long p0 = 0; p0 < (long)n_pts; p0 += (long)cap) {
            int P = (int)(((long)n_pts - p0) < (long)cap ? ((long)n_pts - p0) : (long)cap);
            hipLaunchKernelGGL(pos_prep, dim3((P + 255) / 256), dim3(256), 0, stream,
                               x, pos, (int)p0, P, n_pts);
            hipLaunchKernelGGL(nerf_encode, dim3((P + 255) / 256, NL), dim3(256), 0, stream,
                               pos, (const uint2*)d_ws, dense, enc, rt, dp, P);
            hipLaunchKernelGGL(nerf_mlp_mfma, dim3((P + 63) / 64), dim3(256), 0, stream,
                               wfrag, biasb, enc,
                               dvec, app_idx, app_table,
                               (float*)d_out, (int)p0, P, n_pts);
        }
    } else if (ws_size >= tbl_bytes) {
        int nent = (int)tbl_entries;
        hipLaunchKernelGGL(repack_bf16, dim3((nent + 255) / 256), dim3(256), 0, stream,
                           ht, (unsigned*)d_ws, nent);
        dim3 g((n_pts + 255) / 256), blk(256);
        hipLaunchKernelGGL((nerf_fused<1>), g, blk, 0, stream,
                           x, dvec, app_idx, (const void*)d_ws, app_table,
                           sw0, sb0, sw1, sb1, cw0, cb0, cw1, cb1, cw2, cb2,
                           (float*)d_out, rt, n_pts);
    } else {
        dim3 g((n_pts + 255) / 256), blk(256);
        hipLaunchKernelGGL((nerf_fused<0>), g, blk, 0, stream,
                           x, dvec, app_idx, (const void*)ht, app_table,
                           sw0, sb0, sw1, sb1, cw0, cb0, cw1, cb1, cw2, cb2,
                           (float*)d_out, rt, n_pts);
    }
}

// Round 15
// 916.095 us; speedup vs baseline: 1.2699x; 1.0628x over previous
//
#include <hip/hip_runtime.h>
#include <cmath>
#include <type_traits>

#define NL 16
#define TBL_N (1u << 19)
#define HID 64
#define NDL 6   // dense (coarse) levels

typedef float f4v __attribute__((ext_vector_type(4)));
typedef float f2v __attribute__((ext_vector_type(2)));
typedef short s8v __attribute__((ext_vector_type(8)));
typedef unsigned int u32;
typedef unsigned short u16;

struct Res16 { float r[NL]; };
struct DenseP { int R[NDL]; int off[NDL]; int total; };

__device__ __host__ __forceinline__ unsigned short f2bf(float f) {
    unsigned u = __builtin_bit_cast(unsigned, f);
    unsigned r = (u + 0x7FFFu + ((u >> 16) & 1u)) >> 16;   // RNE
    return (unsigned short)r;
}
__device__ __forceinline__ u32 pack_bf(float a, float b) {
    return (u32)f2bf(a) | ((u32)f2bf(b) << 16);
}
__device__ __forceinline__ void corner_vals(unsigned v, float& f0, float& f1) {
    f0 = __uint_as_float(v << 16);
    f1 = __uint_as_float(v & 0xffff0000u);
}
__device__ __forceinline__ void corner_vals(float2 v, float& f0, float& f1) {
    f0 = v.x; f1 = v.y;
}

__global__ __launch_bounds__(256) void repack_bf16(const float* __restrict__ src,
                                                   unsigned* __restrict__ dst, int n) {
    int i = blockIdx.x * blockDim.x + threadIdx.x;
    if (i >= n) return;
    f2v v = __builtin_nontemporal_load((const f2v*)src + i);
    dst[i] = pack_bf(v.x, v.y);
}

// ======================= Position prepass: pack (px,py,pz) as float4 =======
// TEMPORAL stores: pos is re-read 16x by encode -> let L2/L3 keep it.
__global__ __launch_bounds__(256) void pos_prep(
    const float* __restrict__ x, f4v* __restrict__ pos, int p0, int P, int n_pts)
{
    int p = blockIdx.x * 256 + threadIdx.x;
    if (p >= P) return;
    int n = p0 + p;
    f4v v;
    v.x = (__builtin_nontemporal_load(&x[3*n+0]) + 1.f) * 0.5f;
    v.y = (__builtin_nontemporal_load(&x[3*n+1]) + 1.f) * 0.5f;
    v.z = (__builtin_nontemporal_load(&x[3*n+2]) + 1.f) * 0.5f;
    v.w = 0.f;
    pos[p] = v;
}

// ======================= Build dense quad tables for levels 0..5 ===========
// dense4[cell(X,Y,Z)] = { h(X,Y,Z), h(X,Y,Z+1), h(X,Y+1,Z), h(X,Y+1,Z+1) }
__global__ __launch_bounds__(256) void build_dense4(
    const u32* __restrict__ tbl, uint4* __restrict__ dense, DenseP dp)
{
    int e = blockIdx.x * 256 + threadIdx.x;
    if (e >= dp.total) return;
    int l = 0;
    #pragma unroll
    for (int i = 1; i < NDL; i++) if (e >= dp.off[i]) l = i;
    int cell = e - dp.off[l];
    int R = dp.R[l];
    int Z = cell % R; int t = cell / R; int Y = t % R; int X = t / R;
    u32 hy0 = (u32)Y * 2654435761u, hy1 = hy0 + 2654435761u;
    u32 hz0 = (u32)Z * 805459861u,  hz1 = hz0 + 805459861u;
    const u32* base = tbl + (size_t)l * TBL_N;
    uint4 v;
    v.x = base[((u32)X ^ hy0 ^ hz0) & (TBL_N - 1u)];
    v.y = base[((u32)X ^ hy0 ^ hz1) & (TBL_N - 1u)];
    v.z = base[((u32)X ^ hy1 ^ hz0) & (TBL_N - 1u)];
    v.w = base[((u32)X ^ hy1 ^ hz1) & (TBL_N - 1u)];
    dense[e] = v;
}

// ======================= Kernel E: level-partitioned encode ================
// Dense path: 2x 16B quad loads (X, X+1). Hash path: X-pair uint2 loads.
// Position: single 16B packed TEMPORAL load (L3-resident across levels).
__global__ __launch_bounds__(256) void nerf_encode(
    const f4v* __restrict__ pos,
    const uint2* __restrict__ tbl2,
    const uint4* __restrict__ dense,
    u32* __restrict__ enc,
    Res16 rt, DenseP dp, int P)
{
    int l = blockIdx.y;
    int tid = threadIdx.x;
    int p = blockIdx.x * 256 + tid;
    int pc = min(p, P - 1);

    f4v pv = pos[pc];
    float px = pv.x, py = pv.y, pz = pv.z;

    float res = rt.r[l];
    float xs = px*res, ys = py*res, zs = pz*res;
    float fx = floorf(xs), fy = floorf(ys), fz = floorf(zs);
    float wx = xs - fx, wy = ys - fy, wz = zs - fz;
    float ax = 1.f - wx, ay = 1.f - wy, az = 1.f - wz;

    float e0 = 0.f, e1 = 0.f;
    if (l < NDL) {
        // ---- dense quad path: 2 aligned 16B loads ----
        int R = dp.R[l];
        int X = (int)fx, Y = (int)fy, Z = (int)fz;
        const uint4* dl = dense + dp.off[l];
        int c00 = (X * R + Y) * R + Z;
        uint4 v0 = dl[c00];             // X   : {y0z0,y0z1,y1z0,y1z1}
        uint4 v1 = dl[c00 + R * R];     // X+1
        float s00 = ay*az, s01 = ay*wz, s10 = wy*az, s11 = wy*wz;
        float f0, f1;
        corner_vals(v0.x, f0, f1); e0 += ax*s00*f0; e1 += ax*s00*f1;
        corner_vals(v0.y, f0, f1); e0 += ax*s01*f0; e1 += ax*s01*f1;
        corner_vals(v0.z, f0, f1); e0 += ax*s10*f0; e1 += ax*s10*f1;
        corner_vals(v0.w, f0, f1); e0 += ax*s11*f0; e1 += ax*s11*f1;
        corner_vals(v1.x, f0, f1); e0 += wx*s00*f0; e1 += wx*s00*f1;
        corner_vals(v1.y, f0, f1); e0 += wx*s01*f0; e1 += wx*s01*f1;
        corner_vals(v1.z, f0, f1); e0 += wx*s10*f0; e1 += wx*s10*f1;
        corner_vals(v1.w, f0, f1); e0 += wx*s11*f0; e1 += wx*s11*f1;
    } else {
        // ---- hash path with X-pair uint2 loads ----
        unsigned X = (unsigned)fx;
        unsigned Y = (unsigned)fy, Z = (unsigned)fz;
        unsigned hy0 = Y * 2654435761u, hy1 = hy0 + 2654435761u;
        unsigned hz0 = Z * 805459861u,  hz1 = hz0 + 805459861u;
        bool xodd = (X & 1u) != 0u;
        const uint2* b2 = tbl2 + (size_t)l * (TBL_N / 2);
        #pragma unroll
        for (int c = 0; c < 4; c++) {
            unsigned hyz = ((c & 2) ? hy1 : hy0) ^ ((c & 1) ? hz1 : hz0);
            float wyz = ((c & 2) ? wy : ay) * ((c & 1) ? wz : az);
            unsigned idxA = (X ^ hyz) & (TBL_N - 1u);
            uint2 vA = b2[idxA >> 1];
            u32 a = (idxA & 1u) ? vA.y : vA.x;   // corner X
            u32 b = (idxA & 1u) ? vA.x : vA.y;   // corner X+1 when X even
            if (xodd) {
                unsigned idxB = ((X + 1u) ^ hyz) & (TBL_N - 1u);
                uint2 vB = b2[idxB >> 1];
                b = (idxB & 1u) ? vB.y : vB.x;
            }
            float fa0, fa1, fb0, fb1;
            corner_vals(a, fa0, fa1);
            corner_vals(b, fb0, fb1);
            e0 += wyz * (ax * fa0 + wx * fb0);
            e1 += wyz * (ax * fa1 + wx * fb1);
        }
    }
    __builtin_nontemporal_store(pack_bf(e0, e1), &enc[(size_t)l * P + pc]);
}

// ======================= Pack weights into MFMA A-fragments ================
__global__ __launch_bounds__(256) void nerf_pack_w(
    const float* __restrict__ sw0, const float* __restrict__ sb0,
    const float* __restrict__ sw1, const float* __restrict__ sb1,
    const float* __restrict__ cw0, const float* __restrict__ cb0,
    const float* __restrict__ cw1, const float* __restrict__ cb1,
    const float* __restrict__ cw2, const float* __restrict__ cb2,
    u16* __restrict__ wf, float* __restrict__ bi)
{
    int tid = threadIdx.x;
    for (int e = tid; e < 14336; e += 256) {
        int f = e >> 9, r = e & 511, lane = r >> 3, j = r & 7;
        int fo = lane & 15, G = lane >> 4;
        float val = 0.f;
        if (f < 4) {                       // L0: W = sw0^T, K=32
            int o = f*16 + fo, i = G*8 + j;
            val = sw0[i*64 + o];
        } else if (f < 6) {                // L1: K=64, M=16
            int o = fo, i = (f-4)*32 + G*8 + j;
            val = sw1[i*16 + o];
        } else if (f < 18) {               // C0: K=96 permuted
            int t = f - 6, mt = t / 3, kt = t % 3;
            int o = mt*16 + fo, i = kt*32 + G*8 + j;
            int row = (i < 16) ? (15 + i) : (i < 64) ? (31 + (i - 16)) : (i < 79) ? (i - 64) : -1;
            val = (row < 0) ? 0.f : cw0[row*64 + o];
        } else if (f < 26) {               // C1: K=64
            int t = f - 18, mt = t >> 1, kt = t & 1;
            int o = mt*16 + fo, i = kt*32 + G*8 + j;
            val = cw1[i*64 + o];
        } else {                           // C2: M=16 (3 real), K=64
            int kt = f - 26;
            int o = fo, i = kt*32 + G*8 + j;
            val = (o < 3) ? cw2[i*3 + o] : 0.f;
        }
        wf[e] = f2bf(val);
    }
    for (int i2 = tid; i2 < 224; i2 += 256) {
        float v;
        if (i2 < 64) v = sb0[i2];
        else if (i2 < 80) v = sb1[i2 - 64];
        else if (i2 < 144) v = cb0[i2 - 80];
        else if (i2 < 208) v = cb1[i2 - 144];
        else v = (i2 - 208 < 3) ? cb2[i2 - 208] : 0.f;
        bi[i2] = v;
    }
}

// ======================= Kernel M: MFMA MLP, 256 pts/block =================
// 4 waves; each wave processes 4 groups of 16 points sequentially.
// WF/BI staged ONCE per block (staging traffic / grid count both /4).
#define ASTRIDE 104   // ushorts per point row in ACT (>=96, 16B-multiple)

__global__ __launch_bounds__(256) void nerf_mlp_mfma(
    const u16* __restrict__ wfg, const float* __restrict__ big,
    const u32* __restrict__ enc,
    const float* __restrict__ dvec, const int* __restrict__ app_idx,
    const float* __restrict__ app_table,
    float* __restrict__ out, int p0, int P, int n_pts)
{
    __shared__ __align__(16) u16 WF[14336];
    __shared__ __align__(16) float BI[224];
    __shared__ __align__(16) u16 ACT[4][16 * ASTRIDE];

    int tid = threadIdx.x;
    int w = tid >> 6, l = tid & 63;
    int G = l >> 4, pq = l & 15;

    // stage fragments + biases once
    for (int i = tid; i < 1792; i += 256) ((uint4*)WF)[i] = ((const uint4*)wfg)[i];
    for (int i = tid; i < 224; i += 256) BI[i] = big[i];
    // zero pad region (feats 79..95) once
    if (G == 3) {
        ACT[w][pq*ASTRIDE + 79] = 0;
        #pragma unroll
        for (int k = 0; k < 8; k++) *(u32*)&ACT[w][pq*ASTRIDE + 80 + 2*k] = 0u;
    }
    __syncthreads();

    #pragma unroll 1
    for (int g = 0; g < 4; g++) {
        int pl = blockIdx.x * 256 + w * 64 + g * 16 + pq;
        int pc = min(pl, P - 1);
        int n = p0 + pc;

        uint4 ed;
        {
            const u32* encp = enc + pc;
            ed.x = __builtin_nontemporal_load(encp + (size_t)(4*G+0) * P);
            ed.y = __builtin_nontemporal_load(encp + (size_t)(4*G+1) * P);
            ed.z = __builtin_nontemporal_load(encp + (size_t)(4*G+2) * P);
            ed.w = __builtin_nontemporal_load(encp + (size_t)(4*G+3) * P);
        }
        s8v encf = __builtin_bit_cast(s8v, ed);
        float dx = __builtin_nontemporal_load(&dvec[3*n+0]);
        float dy = __builtin_nontemporal_load(&dvec[3*n+1]);
        float dz = __builtin_nontemporal_load(&dvec[3*n+2]);
        int ai = app_idx[n];
        const f4v* arow = (const f4v*)(app_table + (size_t)ai * 48 + 12 * G);
        f4v a0 = arow[0], a1 = arow[1], a2 = arow[2];

        // ---- L0 ----
        f4v acc0[4];
        #pragma unroll
        for (int mt = 0; mt < 4; mt++) acc0[mt] = *(const f4v*)&BI[mt*16 + 4*G];
        #pragma unroll
        for (int mt = 0; mt < 4; mt++) {
            s8v wfr = *(const s8v*)&WF[mt*512 + l*8];
            acc0[mt] = __builtin_amdgcn_mfma_f32_16x16x32_bf16(wfr, encf, acc0[mt], 0, 0, 0);
        }
        #pragma unroll
        for (int mt = 0; mt < 4; mt++) {
            f4v v = acc0[mt];
            *(u32*)&ACT[w][pq*ASTRIDE + mt*16 + 4*G]     = pack_bf(fmaxf(v[0],0.f), fmaxf(v[1],0.f));
            *(u32*)&ACT[w][pq*ASTRIDE + mt*16 + 4*G + 2] = pack_bf(fmaxf(v[2],0.f), fmaxf(v[3],0.f));
        }

        // ---- L1 (raw) ----
        f4v acc1 = *(const f4v*)&BI[64 + 4*G];
        #pragma unroll
        for (int kt = 0; kt < 2; kt++) {
            s8v b = *(const s8v*)&ACT[w][pq*ASTRIDE + kt*32 + G*8];
            s8v wfr = *(const s8v*)&WF[(4+kt)*512 + l*8];
            acc1 = __builtin_amdgcn_mfma_f32_16x16x32_bf16(wfr, b, acc1, 0, 0, 0);
        }
        float sig_raw = acc1[0];

        // ---- C0 activation build ----
        {
            float invn = 1.0f / sqrtf(dx*dx + dy*dy + dz*dz);
            float ndx = dx*invn, ndy = dy*invn, ndz = dz*invn;
            float xx = ndx*ndx, yy = ndy*ndy, zz = ndz*ndz;
            float xy = ndx*ndy, yz = ndy*ndz, xz = ndx*ndz;
            float s0, s1, s2, s3;
            if (G == 0) {
                s0 =  0.28209479177387814f;
                s1 = -0.48860251190291987f * ndy;
                s2 =  0.48860251190291987f * ndz;
                s3 = -0.48860251190291987f * ndx;
            } else if (G == 1) {
                s0 =  1.0925484305920792f * xy;
                s1 = -1.0925484305920792f * yz;
                s2 =  0.94617469575756f * zz - 0.31539156525252005f;
                s3 = -1.0925484305920792f * xz;
            } else if (G == 2) {
                s0 =  0.5462742152960396f * (xx - yy);
                s1 = -0.5900435899266435f * ndy * (3.f*xx - yy);
                s2 =  2.890611442640554f * xy * ndz;
                s3 = -0.4570457994644657f * ndy * (4.f*zz - xx - yy);
            } else {
                s0 =  0.37317633259011546f * ndz * (2.f*zz - 3.f*xx - 3.f*yy);
                s1 = -0.4570457994644657f * ndx * (4.f*zz - xx - yy);
                s2 =  1.445305721320277f * ndz * (xx - yy);
                s3 = -0.5900435899266435f * ndx * (xx - 3.f*yy);
            }
            *(u32*)&ACT[w][pq*ASTRIDE + 4*G]     = pack_bf(s0, s1);
            *(u32*)&ACT[w][pq*ASTRIDE + 4*G + 2] = pack_bf(s2, s3);
            *(u32*)&ACT[w][pq*ASTRIDE + 16 + 12*G     ] = pack_bf(a0[0], a0[1]);
            *(u32*)&ACT[w][pq*ASTRIDE + 16 + 12*G + 2 ] = pack_bf(a0[2], a0[3]);
            *(u32*)&ACT[w][pq*ASTRIDE + 16 + 12*G + 4 ] = pack_bf(a1[0], a1[1]);
            *(u32*)&ACT[w][pq*ASTRIDE + 16 + 12*G + 6 ] = pack_bf(a1[2], a1[3]);
            *(u32*)&ACT[w][pq*ASTRIDE + 16 + 12*G + 8 ] = pack_bf(a2[0], a2[1]);
            *(u32*)&ACT[w][pq*ASTRIDE + 16 + 12*G + 10] = pack_bf(a2[2], a2[3]);
            #pragma unroll
            for (int r2 = 0; r2 < 4; r2++) {
                int fp = 4*G + r2;
                if (fp >= 1) ACT[w][pq*ASTRIDE + 63 + fp] = f2bf(acc1[r2]);
            }
        }

        // ---- C0 ----
        f4v acc[4];
        #pragma unroll
        for (int mt = 0; mt < 4; mt++) acc[mt] = *(const f4v*)&BI[80 + mt*16 + 4*G];
        #pragma unroll
        for (int kt = 0; kt < 3; kt++) {
            s8v b = *(const s8v*)&ACT[w][pq*ASTRIDE + kt*32 + G*8];
            #pragma unroll
            for (int mt = 0; mt < 4; mt++) {
                s8v wfr = *(const s8v*)&WF[(6 + mt*3 + kt)*512 + l*8];
                acc[mt] = __builtin_amdgcn_mfma_f32_16x16x32_bf16(wfr, b, acc[mt], 0, 0, 0);
            }
        }
        #pragma unroll
        for (int mt = 0; mt < 4; mt++) {
            f4v v = acc[mt];
            *(u32*)&ACT[w][pq*ASTRIDE + mt*16 + 4*G]     = pack_bf(fmaxf(v[0],0.f), fmaxf(v[1],0.f));
            *(u32*)&ACT[w][pq*ASTRIDE + mt*16 + 4*G + 2] = pack_bf(fmaxf(v[2],0.f), fmaxf(v[3],0.f));
        }

        // ---- C1 ----
        #pragma unroll
        for (int mt = 0; mt < 4; mt++) acc[mt] = *(const f4v*)&BI[144 + mt*16 + 4*G];
        #pragma unroll
        for (int kt = 0; kt < 2; kt++) {
            s8v b = *(const s8v*)&ACT[w][pq*ASTRIDE + kt*32 + G*8];
            #pragma unroll
            for (int mt = 0; mt < 4; mt++) {
                s8v wfr = *(const s8v*)&WF[(18 + mt*2 + kt)*512 + l*8];
                acc[mt] = __builtin_amdgcn_mfma_f32_16x16x32_bf16(wfr, b, acc[mt], 0, 0, 0);
            }
        }
        #pragma unroll
        for (int mt = 0; mt < 4; mt++) {
            f4v v = acc[mt];
            *(u32*)&ACT[w][pq*ASTRIDE + mt*16 + 4*G]     = pack_bf(fmaxf(v[0],0.f), fmaxf(v[1],0.f));
            *(u32*)&ACT[w][pq*ASTRIDE + mt*16 + 4*G + 2] = pack_bf(fmaxf(v[2],0.f), fmaxf(v[3],0.f));
        }

        // ---- C2 ----
        f4v acc2 = *(const f4v*)&BI[208 + 4*G];
        #pragma unroll
        for (int kt = 0; kt < 2; kt++) {
            s8v b = *(const s8v*)&ACT[w][pq*ASTRIDE + kt*32 + G*8];
            s8v wfr = *(const s8v*)&WF[(26+kt)*512 + l*8];
            acc2 = __builtin_amdgcn_mfma_f32_16x16x32_bf16(wfr, b, acc2, 0, 0, 0);
        }

        if (G == 0 && pl < P) {
            float z100 = 100.f * sig_raw;
            float sigma = (z100 > 20.f) ? sig_raw : (log1pf(expf(z100)) * 0.01f);
            f4v o4;
            o4[0] = sigma;
            o4[1] = 1.f/(1.f+expf(-acc2[0]));
            o4[2] = 1.f/(1.f+expf(-acc2[1]));
            o4[3] = 1.f/(1.f+expf(-acc2[2]));
            __builtin_nontemporal_store(o4, (f4v*)out + (size_t)(p0 + pl));
        }
    }
}

// ======================= Fused fallback (ws too small) =====================
template <int USE_BF16>
__global__ __launch_bounds__(256) void nerf_fused(
    const float* __restrict__ x,
    const float* __restrict__ dvec,
    const int*   __restrict__ app_idx,
    const void*  __restrict__ tbl_raw,
    const float* __restrict__ app_table,
    const float* __restrict__ sw0, const float* __restrict__ sb0,
    const float* __restrict__ sw1, const float* __restrict__ sb1,
    const float* __restrict__ cw0, const float* __restrict__ cb0,
    const float* __restrict__ cw1, const float* __restrict__ cb1,
    const float* __restrict__ cw2, const float* __restrict__ cb2,
    float* __restrict__ out, Res16 rt, int n_pts)
{
    using CT = typename std::conditional<USE_BF16 != 0, unsigned, float2>::type;
    const CT* __restrict__ tbl = (const CT*)tbl_raw;

    int n = blockIdx.x * blockDim.x + threadIdx.x;
    if (n >= n_pts) return;

    float px = (x[3*n+0] + 1.f) * 0.5f;
    float py = (x[3*n+1] + 1.f) * 0.5f;
    float pz = (x[3*n+2] + 1.f) * 0.5f;

    float e[2*NL];
    #pragma unroll
    for (int l = 0; l < NL; l++) {
        float res = rt.r[l];
        float xs = px*res, ys = py*res, zs = pz*res;
        float fx = floorf(xs), fy = floorf(ys), fz = floorf(zs);
        float wx = xs - fx, wy = ys - fy, wz = zs - fz;
        float ax = 1.f - wx, ay = 1.f - wy, az = 1.f - wz;
        unsigned X = (unsigned)fx, Y = (unsigned)fy, Z = (unsigned)fz;
        unsigned hx0 = X,               hx1 = X + 1u;
        unsigned hy0 = Y * 2654435761u, hy1 = hy0 + 2654435761u;
        unsigned hz0 = Z * 805459861u,  hz1 = hz0 + 805459861u;
        const CT* base = tbl + (size_t)l * TBL_N;
        float e0 = 0.f, e1 = 0.f;
        #pragma unroll
        for (int c = 0; c < 8; c++) {
            unsigned idx = (((c & 4) ? hx1 : hx0) ^
                            ((c & 2) ? hy1 : hy0) ^
                            ((c & 1) ? hz1 : hz0)) & (TBL_N - 1u);
            CT v = base[idx];
            float f0, f1;
            corner_vals(v, f0, f1);
            float wgt = ((c & 4) ? wx : ax) * ((c & 2) ? wy : ay) * ((c & 1) ? wz : az);
            e0 += wgt * f0;
            e1 += wgt * f1;
        }
        e[2*l] = e0; e[2*l+1] = e1;
    }

    float h[HID];
    #pragma unroll
    for (int o = 0; o < HID; o++) h[o] = sb0[o];
    #pragma unroll
    for (int l = 0; l < NL; l++) {
        const float* r0 = sw0 + (2 * l) * HID;
        float e0 = e[2*l], e1 = e[2*l+1];
        #pragma unroll
        for (int o = 0; o < HID; o++) h[o] += e0 * r0[o] + e1 * r0[HID + o];
    }
    #pragma unroll
    for (int o = 0; o < HID; o++) h[o] = fmaxf(h[o], 0.f);

    float h1[16];
    #pragma unroll
    for (int o = 0; o < 16; o++) h1[o] = sb1[o];
    #pragma unroll
    for (int i = 0; i < HID; i++) {
        float v = h[i];
        const float* wr = sw1 + i * 16;
        #pragma unroll
        for (int o = 0; o < 16; o++) h1[o] += v * wr[o];
    }

    float z100 = 100.f * h1[0];
    float sigma = (z100 > 20.f) ? h1[0] : (log1pf(expf(z100)) * 0.01f);

    float dx = dvec[3*n+0], dy = dvec[3*n+1], dz = dvec[3*n+2];
    float invn = 1.0f / sqrtf(dx*dx + dy*dy + dz*dz);
    dx *= invn; dy *= invn; dz *= invn;
    float xx = dx*dx, yy = dy*dy, zz = dz*dz;
    float xy = dx*dy, yz = dy*dz, xz = dx*dz;
    float sh[16];
    sh[0]  = 0.28209479177387814f;
    sh[1]  = -0.48860251190291987f * dy;
    sh[2]  =  0.48860251190291987f * dz;
    sh[3]  = -0.48860251190291987f * dx;
    sh[4]  =  1.0925484305920792f * xy;
    sh[5]  = -1.0925484305920792f * yz;
    sh[6]  =  0.94617469575756f * zz - 0.31539156525252005f;
    sh[7]  = -1.0925484305920792f * xz;
    sh[8]  =  0.5462742152960396f * (xx - yy);
    sh[9]  = -0.5900435899266435f * dy * (3.f * xx - yy);
    sh[10] =  2.890611442640554f * xy * dz;
    sh[11] = -0.4570457994644657f * dy * (4.f * zz - xx - yy);
    sh[12] =  0.37317633259011546f * dz * (2.f * zz - 3.f * xx - 3.f * yy);
    sh[13] = -0.4570457994644657f * dx * (4.f * zz - xx - yy);
    sh[14] =  1.445305721320277f * dz * (xx - yy);
    sh[15] = -0.5900435899266435f * dx * (xx - 3.f * yy);

    float c1[HID];
    #pragma unroll
    for (int o = 0; o < HID; o++) c1[o] = cb0[o];
    #pragma unroll
    for (int i = 0; i < 15; i++) {
        float v = h1[i + 1];
        const float* wr = cw0 + i * HID;
        #pragma unroll
        for (int o = 0; o < HID; o++) c1[o] += v * wr[o];
    }
    #pragma unroll
    for (int i = 0; i < 16; i++) {
        float v = sh[i];
        const float* wr = cw0 + (15 + i) * HID;
        #pragma unroll
        for (int o = 0; o < HID; o++) c1[o] += v * wr[o];
    }
    {
        const float4* arow = reinterpret_cast<const float4*>(app_table + (size_t)app_idx[n] * 48);
        for (int j4 = 0; j4 < 12; j4++) {
            float4 v = arow[j4];
            const float* wr = cw0 + (31 + 4 * j4) * HID;
            #pragma unroll
            for (int o = 0; o < HID; o++) c1[o] += v.x * wr[o];
            #pragma unroll
            for (int o = 0; o < HID; o++) c1[o] += v.y * wr[HID + o];
            #pragma unroll
            for (int o = 0; o < HID; o++) c1[o] += v.z * wr[2 * HID + o];
            #pragma unroll
            for (int o = 0; o < HID; o++) c1[o] += v.w * wr[3 * HID + o];
        }
    }
    #pragma unroll
    for (int o = 0; o < HID; o++) c1[o] = fmaxf(c1[o], 0.f);

    float c2[HID];
    #pragma unroll
    for (int o = 0; o < HID; o++) c2[o] = cb1[o];
    #pragma unroll
    for (int i = 0; i < HID; i++) {
        float v = c1[i];
        const float* wr = cw1 + i * HID;
        #pragma unroll
        for (int o = 0; o < HID; o++) c2[o] += v * wr[o];
    }
    #pragma unroll
    for (int o = 0; o < HID; o++) c2[o] = fmaxf(c2[o], 0.f);

    float r = cb2[0], g = cb2[1], b = cb2[2];
    #pragma unroll
    for (int i = 0; i < HID; i++) {
        float v = c2[i];
        r += v * cw2[i * 3 + 0];
        g += v * cw2[i * 3 + 1];
        b += v * cw2[i * 3 + 2];
    }
    r = 1.f / (1.f + expf(-r));
    g = 1.f / (1.f + expf(-g));
    b = 1.f / (1.f + expf(-b));

    reinterpret_cast<float4*>(out)[n] = make_float4(sigma, r, g, b);
}

extern "C" void kernel_launch(void* const* d_in, const int* in_sizes, int n_in,
                              void* d_out, int out_size, void* d_ws, size_t ws_size,
                              hipStream_t stream) {
    const float* x         = (const float*)d_in[0];
    const float* dvec      = (const float*)d_in[1];
    const int*   app_idx   = (const int*)  d_in[2];
    const float* ht        = (const float*)d_in[3];
    const float* app_table = (const float*)d_in[4];
    const float* sw0 = (const float*)d_in[5];
    const float* sb0 = (const float*)d_in[6];
    const float* sw1 = (const float*)d_in[7];
    const float* sb1 = (const float*)d_in[8];
    const float* cw0 = (const float*)d_in[9];
    const float* cb0 = (const float*)d_in[10];
    const float* cw1 = (const float*)d_in[11];
    const float* cb1 = (const float*)d_in[12];
    const float* cw2 = (const float*)d_in[13];
    const float* cb2 = (const float*)d_in[14];

    int n_pts = in_sizes[0] / 3;

    Res16 rt;
    double bb = exp(log(2048.0 / 16.0) / 15.0);
    for (int l = 0; l < NL; l++) rt.r[l] = (float)floor(16.0 * pow(bb, (double)l));

    DenseP dp;
    {
        int acc = 0;
        for (int l = 0; l < NDL; l++) {
            dp.R[l] = (int)rt.r[l] + 1;
            dp.off[l] = acc;
            acc += dp.R[l] * dp.R[l] * dp.R[l];
        }
        dp.total = acc;
    }

    const size_t tbl_entries = (size_t)NL * TBL_N;
    const size_t tbl_bytes = tbl_entries * sizeof(unsigned);       // 32 MiB
    const size_t WFRAG_OFF = tbl_bytes;
    const size_t BIAS_OFF  = WFRAG_OFF + 14336 * 2;
    const size_t DENSE_OFF = (BIAS_OFF + 224 * 4 + 255) & ~(size_t)255;
    const size_t CHUNK_OFF = (DENSE_OFF + (size_t)dp.total * 16 + 255) & ~(size_t)255;

    if (ws_size >= CHUNK_OFF + (8u << 20)) {
        int nent = (int)tbl_entries;
        hipLaunchKernelGGL(repack_bf16, dim3((nent + 255) / 256), dim3(256), 0, stream,
                           ht, (unsigned*)d_ws, nent);
        u16*   wfrag = (u16*)  ((char*)d_ws + WFRAG_OFF);
        float* biasb = (float*)((char*)d_ws + BIAS_OFF);
        uint4* dense = (uint4*)((char*)d_ws + DENSE_OFF);
        hipLaunchKernelGGL(nerf_pack_w, dim3(1), dim3(256), 0, stream,
                           sw0, sb0, sw1, sb1, cw0, cb0, cw1, cb1, cw2, cb2,
                           wfrag, biasb);
        hipLaunchKernelGGL(build_dense4, dim3((dp.total + 255) / 256), dim3(256), 0, stream,
                           (const u32*)d_ws, dense, dp);

        // chunk region: pos (16 B/pt) + enc (64 B/pt) = 80 B/pt
        size_t cap = (ws_size - CHUNK_OFF) / 80;
        if (cap > (size_t)n_pts) cap = (size_t)n_pts;
        cap &= ~(size_t)255;
        if (cap == 0) cap = 256;
        f4v* pos = (f4v*)((char*)d_ws + CHUNK_OFF);
        u32* enc = (u32*)((char*)d_ws + CHUNK_OFF + cap * 16);

        for (long p0 = 0; p0 < (long)n_pts; p0 += (long)cap) {
            int P = (int)(((long)n_pts - p0) < (long)cap ? ((long)n_pts - p0) : (long)cap);
            hipLaunchKernelGGL(pos_prep, dim3((P + 255) / 256), dim3(256), 0, stream,
                               x, pos, (int)p0, P, n_pts);
            hipLaunchKernelGGL(nerf_encode, dim3((P + 255) / 256, NL), dim3(256), 0, stream,
                               pos, (const uint2*)d_ws, dense, enc, rt, dp, P);
            hipLaunchKernelGGL(nerf_mlp_mfma, dim3((P + 255) / 256), dim3(256), 0, stream,
                               wfrag, biasb, enc,
                               dvec, app_idx, app_table,
                               (float*)d_out, (int)p0, P, n_pts);
        }
    } else if (ws_size >= tbl_bytes) {
        int nent = (int)tbl_entries;
        hipLaunchKernelGGL(repack_bf16, dim3((nent + 255) / 256), dim3(256), 0, stream,
                           ht, (unsigned*)d_ws, nent);
        dim3 g((n_pts + 255) / 256), blk(256);
        hipLaunchKernelGGL((nerf_fused<1>), g, blk, 0, stream,
                           x, dvec, app_idx, (const void*)d_ws, app_table,
                           sw0, sb0, sw1, sb1, cw0, cb0, cw1, cb1, cw2, cb2,
                           (float*)d_out, rt, n_pts);
    } else {
        dim3 g((n_pts + 255) / 256), blk(256);
        hipLaunchKernelGGL((nerf_fused<0>), g, blk, 0, stream,
                           x, dvec, app_idx, (const void*)ht, app_table,
                           sw0, sb0, sw1, sb1, cw0, cb0, cw1, cb1, cw2, cb2,
                           (float*)d_out, rt, n_pts);
    }
}

// Round 16
// 784.103 us; speedup vs baseline: 1.4836x; 1.1683x over previous
//
#include <hip/hip_runtime.h>
#include <cmath>
#include <type_traits>

#define NL 16
#define TBL_N (1u << 19)
#define HID 64
#define NDL 6   // dense (coarse) levels

typedef float f4v __attribute__((ext_vector_type(4)));
typedef float f2v __attribute__((ext_vector_type(2)));
typedef short s8v __attribute__((ext_vector_type(8)));
typedef unsigned int u32;
typedef unsigned short u16;

struct Res16 { float r[NL]; };
struct DenseP { int R[NDL]; int off[NDL]; int total; };

__device__ __host__ __forceinline__ unsigned short f2bf(float f) {
    unsigned u = __builtin_bit_cast(unsigned, f);
    unsigned r = (u + 0x7FFFu + ((u >> 16) & 1u)) >> 16;   // RNE
    return (unsigned short)r;
}
__device__ __forceinline__ u32 pack_bf(float a, float b) {
    return (u32)f2bf(a) | ((u32)f2bf(b) << 16);
}
__device__ __forceinline__ void corner_vals(unsigned v, float& f0, float& f1) {
    f0 = __uint_as_float(v << 16);
    f1 = __uint_as_float(v & 0xffff0000u);
}
__device__ __forceinline__ u32 sel4(uint4 v, unsigned i) {
    u32 lo = (i & 1u) ? v.y : v.x;
    u32 hi = (i & 1u) ? v.w : v.z;
    return (i & 2u) ? hi : lo;
}

__global__ __launch_bounds__(256) void repack_bf16(const float* __restrict__ src,
                                                   unsigned* __restrict__ dst, int n) {
    int i = blockIdx.x * blockDim.x + threadIdx.x;
    if (i >= n) return;
    f2v v = __builtin_nontemporal_load((const f2v*)src + i);
    dst[i] = pack_bf(v.x, v.y);
}

// ======================= Position prepass ==================================
__global__ __launch_bounds__(256) void pos_prep(
    const float* __restrict__ x, f4v* __restrict__ pos, int p0, int P, int n_pts)
{
    int p = blockIdx.x * 256 + threadIdx.x;
    if (p >= P) return;
    int n = p0 + p;
    f4v v;
    v.x = (__builtin_nontemporal_load(&x[3*n+0]) + 1.f) * 0.5f;
    v.y = (__builtin_nontemporal_load(&x[3*n+1]) + 1.f) * 0.5f;
    v.z = (__builtin_nontemporal_load(&x[3*n+2]) + 1.f) * 0.5f;
    v.w = 0.f;
    pos[p] = v;
}

// ======================= Build dense quad tables for levels 0..5 ===========
__global__ __launch_bounds__(256) void build_dense4(
    const u32* __restrict__ tbl, uint4* __restrict__ dense, DenseP dp)
{
    int e = blockIdx.x * 256 + threadIdx.x;
    if (e >= dp.total) return;
    int l = 0;
    #pragma unroll
    for (int i = 1; i < NDL; i++) if (e >= dp.off[i]) l = i;
    int cell = e - dp.off[l];
    int R = dp.R[l];
    int Z = cell % R; int t = cell / R; int Y = t % R; int X = t / R;
    u32 hy0 = (u32)Y * 2654435761u, hy1 = hy0 + 2654435761u;
    u32 hz0 = (u32)Z * 805459861u,  hz1 = hz0 + 805459861u;
    const u32* base = tbl + (size_t)l * TBL_N;
    uint4 v;
    v.x = base[((u32)X ^ hy0 ^ hz0) & (TBL_N - 1u)];
    v.y = base[((u32)X ^ hy0 ^ hz1) & (TBL_N - 1u)];
    v.z = base[((u32)X ^ hy1 ^ hz0) & (TBL_N - 1u)];
    v.w = base[((u32)X ^ hy1 ^ hz1) & (TBL_N - 1u)];
    dense[e] = v;
}

// ======================= Kernel E: level-partitioned encode ================
// Dense path: 2x 16B quad loads. Hash path: aligned-quad loads — one uint4
// covers BOTH X-corners for 3/4 of points (X mod 4 != 3); exec-masked second
// quad load otherwise. ~5 lookups/pt/level.
__global__ __launch_bounds__(256) void nerf_encode(
    const f4v* __restrict__ pos,
    const uint4* __restrict__ tbl4,
    const uint4* __restrict__ dense,
    u32* __restrict__ enc,
    Res16 rt, DenseP dp, int P)
{
    int l = blockIdx.y;
    int tid = threadIdx.x;
    int p = blockIdx.x * 256 + tid;
    int pc = min(p, P - 1);

    f4v pv = pos[pc];
    float px = pv.x, py = pv.y, pz = pv.z;

    float res = rt.r[l];
    float xs = px*res, ys = py*res, zs = pz*res;
    float fx = floorf(xs), fy = floorf(ys), fz = floorf(zs);
    float wx = xs - fx, wy = ys - fy, wz = zs - fz;
    float ax = 1.f - wx, ay = 1.f - wy, az = 1.f - wz;

    float e0 = 0.f, e1 = 0.f;
    if (l < NDL) {
        int R = dp.R[l];
        int X = (int)fx, Y = (int)fy, Z = (int)fz;
        const uint4* dl = dense + dp.off[l];
        int c00 = (X * R + Y) * R + Z;
        uint4 v0 = dl[c00];             // X   : {y0z0,y0z1,y1z0,y1z1}
        uint4 v1 = dl[c00 + R * R];     // X+1
        float s00 = ay*az, s01 = ay*wz, s10 = wy*az, s11 = wy*wz;
        float f0, f1;
        corner_vals(v0.x, f0, f1); e0 += ax*s00*f0; e1 += ax*s00*f1;
        corner_vals(v0.y, f0, f1); e0 += ax*s01*f0; e1 += ax*s01*f1;
        corner_vals(v0.z, f0, f1); e0 += ax*s10*f0; e1 += ax*s10*f1;
        corner_vals(v0.w, f0, f1); e0 += ax*s11*f0; e1 += ax*s11*f1;
        corner_vals(v1.x, f0, f1); e0 += wx*s00*f0; e1 += wx*s00*f1;
        corner_vals(v1.y, f0, f1); e0 += wx*s01*f0; e1 += wx*s01*f1;
        corner_vals(v1.z, f0, f1); e0 += wx*s10*f0; e1 += wx*s10*f1;
        corner_vals(v1.w, f0, f1); e0 += wx*s11*f0; e1 += wx*s11*f1;
    } else {
        unsigned X = (unsigned)fx, Xp = X + 1u;
        unsigned Y = (unsigned)fy, Z = (unsigned)fz;
        unsigned hy0 = Y * 2654435761u, hy1 = hy0 + 2654435761u;
        unsigned hz0 = Z * 805459861u,  hz1 = hz0 + 805459861u;
        const uint4* b4 = tbl4 + (size_t)l * (TBL_N / 4);
        #pragma unroll
        for (int c = 0; c < 4; c++) {
            unsigned hyz = ((c & 2) ? hy1 : hy0) ^ ((c & 1) ? hz1 : hz0);
            float wyz = ((c & 2) ? wy : ay) * ((c & 1) ? wz : az);
            unsigned idxA = (X  ^ hyz) & (TBL_N - 1u);
            unsigned idxB = (Xp ^ hyz) & (TBL_N - 1u);
            uint4 vA = b4[idxA >> 2];
            u32 a = sel4(vA, idxA & 3u);
            u32 b;
            if ((idxB >> 2) == (idxA >> 2)) {
                b = sel4(vA, idxB & 3u);
            } else {
                uint4 vB = b4[idxB >> 2];
                b = sel4(vB, idxB & 3u);
            }
            float fa0, fa1, fb0, fb1;
            corner_vals(a, fa0, fa1);
            corner_vals(b, fb0, fb1);
            e0 += wyz * (ax * fa0 + wx * fb0);
            e1 += wyz * (ax * fa1 + wx * fb1);
        }
    }
    __builtin_nontemporal_store(pack_bf(e0, e1), &enc[(size_t)l * P + pc]);
}

// ======================= Pack weights into MFMA A-fragments ================
__global__ __launch_bounds__(256) void nerf_pack_w(
    const float* __restrict__ sw0, const float* __restrict__ sb0,
    const float* __restrict__ sw1, const float* __restrict__ sb1,
    const float* __restrict__ cw0, const float* __restrict__ cb0,
    const float* __restrict__ cw1, const float* __restrict__ cb1,
    const float* __restrict__ cw2, const float* __restrict__ cb2,
    u16* __restrict__ wf, float* __restrict__ bi)
{
    int tid = threadIdx.x;
    for (int e = tid; e < 14336; e += 256) {
        int f = e >> 9, r = e & 511, lane = r >> 3, j = r & 7;
        int fo = lane & 15, G = lane >> 4;
        float val = 0.f;
        if (f < 4) {                       // L0: W = sw0^T, K=32
            int o = f*16 + fo, i = G*8 + j;
            val = sw0[i*64 + o];
        } else if (f < 6) {                // L1: K=64, M=16
            int o = fo, i = (f-4)*32 + G*8 + j;
            val = sw1[i*16 + o];
        } else if (f < 18) {               // C0: K=96 permuted
            int t = f - 6, mt = t / 3, kt = t % 3;
            int o = mt*16 + fo, i = kt*32 + G*8 + j;
            int row = (i < 16) ? (15 + i) : (i < 64) ? (31 + (i - 16)) : (i < 79) ? (i - 64) : -1;
            val = (row < 0) ? 0.f : cw0[row*64 + o];
        } else if (f < 26) {               // C1: K=64
            int t = f - 18, mt = t >> 1, kt = t & 1;
            int o = mt*16 + fo, i = kt*32 + G*8 + j;
            val = cw1[i*64 + o];
        } else {                           // C2: M=16 (3 real), K=64
            int kt = f - 26;
            int o = fo, i = kt*32 + G*8 + j;
            val = (o < 3) ? cw2[i*3 + o] : 0.f;
        }
        wf[e] = f2bf(val);
    }
    for (int i2 = tid; i2 < 224; i2 += 256) {
        float v;
        if (i2 < 64) v = sb0[i2];
        else if (i2 < 80) v = sb1[i2 - 64];
        else if (i2 < 144) v = cb0[i2 - 80];
        else if (i2 < 208) v = cb1[i2 - 144];
        else v = (i2 - 208 < 3) ? cb2[i2 - 208] : 0.f;
        bi[i2] = v;
    }
}

// ======================= Kernel M: MFMA MLP, weights in VGPRs ==============
// 256 pts/block, 4 groups/wave. 28 A-frags live in registers (loaded once,
// coalesced, L2-hit) -> LDS pipe only carries activation traffic.
#define ASTRIDE 104   // ushorts per point row in ACT (>=96, 16B-multiple)

__global__ __launch_bounds__(256) void nerf_mlp_mfma(
    const u16* __restrict__ wfg, const float* __restrict__ big,
    const u32* __restrict__ enc,
    const float* __restrict__ dvec, const int* __restrict__ app_idx,
    const float* __restrict__ app_table,
    float* __restrict__ out, int p0, int P, int n_pts)
{
    __shared__ __align__(16) float BI[224];
    __shared__ __align__(16) u16 ACT[4][16 * ASTRIDE];

    int tid = threadIdx.x;
    int w = tid >> 6, l = tid & 63;
    int G = l >> 4, pq = l & 15;

    // weight fragments -> registers (static indices only)
    s8v wreg[28];
    #pragma unroll
    for (int f = 0; f < 28; f++)
        wreg[f] = *(const s8v*)(wfg + f * 512 + l * 8);

    for (int i = tid; i < 224; i += 256) BI[i] = big[i];
    if (G == 3) {
        ACT[w][pq*ASTRIDE + 79] = 0;
        #pragma unroll
        for (int k = 0; k < 8; k++) *(u32*)&ACT[w][pq*ASTRIDE + 80 + 2*k] = 0u;
    }
    __syncthreads();

    #pragma unroll 1
    for (int g = 0; g < 4; g++) {
        int pl = blockIdx.x * 256 + w * 64 + g * 16 + pq;
        int pc = min(pl, P - 1);
        int n = p0 + pc;

        uint4 ed;
        {
            const u32* encp = enc + pc;
            ed.x = __builtin_nontemporal_load(encp + (size_t)(4*G+0) * P);
            ed.y = __builtin_nontemporal_load(encp + (size_t)(4*G+1) * P);
            ed.z = __builtin_nontemporal_load(encp + (size_t)(4*G+2) * P);
            ed.w = __builtin_nontemporal_load(encp + (size_t)(4*G+3) * P);
        }
        s8v encf = __builtin_bit_cast(s8v, ed);
        float dx = __builtin_nontemporal_load(&dvec[3*n+0]);
        float dy = __builtin_nontemporal_load(&dvec[3*n+1]);
        float dz = __builtin_nontemporal_load(&dvec[3*n+2]);
        int ai = app_idx[n];
        const f4v* arow = (const f4v*)(app_table + (size_t)ai * 48 + 12 * G);
        f4v a0 = arow[0], a1 = arow[1], a2 = arow[2];

        // ---- L0 ----
        f4v acc0[4];
        #pragma unroll
        for (int mt = 0; mt < 4; mt++) acc0[mt] = *(const f4v*)&BI[mt*16 + 4*G];
        #pragma unroll
        for (int mt = 0; mt < 4; mt++)
            acc0[mt] = __builtin_amdgcn_mfma_f32_16x16x32_bf16(wreg[mt], encf, acc0[mt], 0, 0, 0);
        #pragma unroll
        for (int mt = 0; mt < 4; mt++) {
            f4v v = acc0[mt];
            *(u32*)&ACT[w][pq*ASTRIDE + mt*16 + 4*G]     = pack_bf(fmaxf(v[0],0.f), fmaxf(v[1],0.f));
            *(u32*)&ACT[w][pq*ASTRIDE + mt*16 + 4*G + 2] = pack_bf(fmaxf(v[2],0.f), fmaxf(v[3],0.f));
        }

        // ---- L1 (raw) ----
        f4v acc1 = *(const f4v*)&BI[64 + 4*G];
        #pragma unroll
        for (int kt = 0; kt < 2; kt++) {
            s8v b = *(const s8v*)&ACT[w][pq*ASTRIDE + kt*32 + G*8];
            acc1 = __builtin_amdgcn_mfma_f32_16x16x32_bf16(wreg[4+kt], b, acc1, 0, 0, 0);
        }
        float sig_raw = acc1[0];

        // ---- C0 activation build ----
        {
            float invn = 1.0f / sqrtf(dx*dx + dy*dy + dz*dz);
            float ndx = dx*invn, ndy = dy*invn, ndz = dz*invn;
            float xx = ndx*ndx, yy = ndy*ndy, zz = ndz*ndz;
            float xy = ndx*ndy, yz = ndy*ndz, xz = ndx*ndz;
            float s0, s1, s2, s3;
            if (G == 0) {
                s0 =  0.28209479177387814f;
                s1 = -0.48860251190291987f * ndy;
                s2 =  0.48860251190291987f * ndz;
                s3 = -0.48860251190291987f * ndx;
            } else if (G == 1) {
                s0 =  1.0925484305920792f * xy;
                s1 = -1.0925484305920792f * yz;
                s2 =  0.94617469575756f * zz - 0.31539156525252005f;
                s3 = -1.0925484305920792f * xz;
            } else if (G == 2) {
                s0 =  0.5462742152960396f * (xx - yy);
                s1 = -0.5900435899266435f * ndy * (3.f*xx - yy);
                s2 =  2.890611442640554f * xy * ndz;
                s3 = -0.4570457994644657f * ndy * (4.f*zz - xx - yy);
            } else {
                s0 =  0.37317633259011546f * ndz * (2.f*zz - 3.f*xx - 3.f*yy);
                s1 = -0.4570457994644657f * ndx * (4.f*zz - xx - yy);
                s2 =  1.445305721320277f * ndz * (xx - yy);
                s3 = -0.5900435899266435f * ndx * (xx - 3.f*yy);
            }
            *(u32*)&ACT[w][pq*ASTRIDE + 4*G]     = pack_bf(s0, s1);
            *(u32*)&ACT[w][pq*ASTRIDE + 4*G + 2] = pack_bf(s2, s3);
            *(u32*)&ACT[w][pq*ASTRIDE + 16 + 12*G     ] = pack_bf(a0[0], a0[1]);
            *(u32*)&ACT[w][pq*ASTRIDE + 16 + 12*G + 2 ] = pack_bf(a0[2], a0[3]);
            *(u32*)&ACT[w][pq*ASTRIDE + 16 + 12*G + 4 ] = pack_bf(a1[0], a1[1]);
            *(u32*)&ACT[w][pq*ASTRIDE + 16 + 12*G + 6 ] = pack_bf(a1[2], a1[3]);
            *(u32*)&ACT[w][pq*ASTRIDE + 16 + 12*G + 8 ] = pack_bf(a2[0], a2[1]);
            *(u32*)&ACT[w][pq*ASTRIDE + 16 + 12*G + 10] = pack_bf(a2[2], a2[3]);
            #pragma unroll
            for (int r2 = 0; r2 < 4; r2++) {
                int fp = 4*G + r2;
                if (fp >= 1) ACT[w][pq*ASTRIDE + 63 + fp] = f2bf(acc1[r2]);
            }
        }

        // ---- C0 ----
        f4v acc[4];
        #pragma unroll
        for (int mt = 0; mt < 4; mt++) acc[mt] = *(const f4v*)&BI[80 + mt*16 + 4*G];
        #pragma unroll
        for (int kt = 0; kt < 3; kt++) {
            s8v b = *(const s8v*)&ACT[w][pq*ASTRIDE + kt*32 + G*8];
            #pragma unroll
            for (int mt = 0; mt < 4; mt++)
                acc[mt] = __builtin_amdgcn_mfma_f32_16x16x32_bf16(wreg[6 + mt*3 + kt], b, acc[mt], 0, 0, 0);
        }
        #pragma unroll
        for (int mt = 0; mt < 4; mt++) {
            f4v v = acc[mt];
            *(u32*)&ACT[w][pq*ASTRIDE + mt*16 + 4*G]     = pack_bf(fmaxf(v[0],0.f), fmaxf(v[1],0.f));
            *(u32*)&ACT[w][pq*ASTRIDE + mt*16 + 4*G + 2] = pack_bf(fmaxf(v[2],0.f), fmaxf(v[3],0.f));
        }

        // ---- C1 ----
        #pragma unroll
        for (int mt = 0; mt < 4; mt++) acc[mt] = *(const f4v*)&BI[144 + mt*16 + 4*G];
        #pragma unroll
        for (int kt = 0; kt < 2; kt++) {
            s8v b = *(const s8v*)&ACT[w][pq*ASTRIDE + kt*32 + G*8];
            #pragma unroll
            for (int mt = 0; mt < 4; mt++)
                acc[mt] = __builtin_amdgcn_mfma_f32_16x16x32_bf16(wreg[18 + mt*2 + kt], b, acc[mt], 0, 0, 0);
        }
        #pragma unroll
        for (int mt = 0; mt < 4; mt++) {
            f4v v = acc[mt];
            *(u32*)&ACT[w][pq*ASTRIDE + mt*16 + 4*G]     = pack_bf(fmaxf(v[0],0.f), fmaxf(v[1],0.f));
            *(u32*)&ACT[w][pq*ASTRIDE + mt*16 + 4*G + 2] = pack_bf(fmaxf(v[2],0.f), fmaxf(v[3],0.f));
        }

        // ---- C2 ----
        f4v acc2 = *(const f4v*)&BI[208 + 4*G];
        #pragma unroll
        for (int kt = 0; kt < 2; kt++) {
            s8v b = *(const s8v*)&ACT[w][pq*ASTRIDE + kt*32 + G*8];
            acc2 = __builtin_amdgcn_mfma_f32_16x16x32_bf16(wreg[26+kt], b, acc2, 0, 0, 0);
        }

        if (G == 0 && pl < P) {
            float z100 = 100.f * sig_raw;
            float sigma = (z100 > 20.f) ? sig_raw : (log1pf(expf(z100)) * 0.01f);
            f4v o4;
            o4[0] = sigma;
            o4[1] = 1.f/(1.f+expf(-acc2[0]));
            o4[2] = 1.f/(1.f+expf(-acc2[1]));
            o4[3] = 1.f/(1.f+expf(-acc2[2]));
            __builtin_nontemporal_store(o4, (f4v*)out + (size_t)(p0 + pl));
        }
    }
}

// ======================= Fused fallback (ws too small) =====================
template <int USE_BF16>
__global__ __launch_bounds__(256) void nerf_fused(
    const float* __restrict__ x,
    const float* __restrict__ dvec,
    const int*   __restrict__ app_idx,
    const void*  __restrict__ tbl_raw,
    const float* __restrict__ app_table,
    const float* __restrict__ sw0, const float* __restrict__ sb0,
    const float* __restrict__ sw1, const float* __restrict__ sb1,
    const float* __restrict__ cw0, const float* __restrict__ cb0,
    const float* __restrict__ cw1, const float* __restrict__ cb1,
    const float* __restrict__ cw2, const float* __restrict__ cb2,
    float* __restrict__ out, Res16 rt, int n_pts)
{
    using CT = typename std::conditional<USE_BF16 != 0, unsigned, float2>::type;
    const CT* __restrict__ tbl = (const CT*)tbl_raw;

    int n = blockIdx.x * blockDim.x + threadIdx.x;
    if (n >= n_pts) return;

    float px = (x[3*n+0] + 1.f) * 0.5f;
    float py = (x[3*n+1] + 1.f) * 0.5f;
    float pz = (x[3*n+2] + 1.f) * 0.5f;

    float e[2*NL];
    #pragma unroll
    for (int l = 0; l < NL; l++) {
        float res = rt.r[l];
        float xs = px*res, ys = py*res, zs = pz*res;
        float fx = floorf(xs), fy = floorf(ys), fz = floorf(zs);
        float wx = xs - fx, wy = ys - fy, wz = zs - fz;
        float ax = 1.f - wx, ay = 1.f - wy, az = 1.f - wz;
        unsigned X = (unsigned)fx, Y = (unsigned)fy, Z = (unsigned)fz;
        unsigned hx0 = X,               hx1 = X + 1u;
        unsigned hy0 = Y * 2654435761u, hy1 = hy0 + 2654435761u;
        unsigned hz0 = Z * 805459861u,  hz1 = hz0 + 805459861u;
        const CT* base = tbl + (size_t)l * TBL_N;
        float e0 = 0.f, e1 = 0.f;
        #pragma unroll
        for (int c = 0; c < 8; c++) {
            unsigned idx = (((c & 4) ? hx1 : hx0) ^
                            ((c & 2) ? hy1 : hy0) ^
                            ((c & 1) ? hz1 : hz0)) & (TBL_N - 1u);
            CT v = base[idx];
            float f0, f1;
            if constexpr (USE_BF16 != 0) { corner_vals((unsigned)v, f0, f1); }
            else { float2 vv = *(float2*)&v; f0 = vv.x; f1 = vv.y; }
            float wgt = ((c & 4) ? wx : ax) * ((c & 2) ? wy : ay) * ((c & 1) ? wz : az);
            e0 += wgt * f0;
            e1 += wgt * f1;
        }
        e[2*l] = e0; e[2*l+1] = e1;
    }

    float h[HID];
    #pragma unroll
    for (int o = 0; o < HID; o++) h[o] = sb0[o];
    #pragma unroll
    for (int l = 0; l < NL; l++) {
        const float* r0 = sw0 + (2 * l) * HID;
        float e0 = e[2*l], e1 = e[2*l+1];
        #pragma unroll
        for (int o = 0; o < HID; o++) h[o] += e0 * r0[o] + e1 * r0[HID + o];
    }
    #pragma unroll
    for (int o = 0; o < HID; o++) h[o] = fmaxf(h[o], 0.f);

    float h1[16];
    #pragma unroll
    for (int o = 0; o < 16; o++) h1[o] = sb1[o];
    #pragma unroll
    for (int i = 0; i < HID; i++) {
        float v = h[i];
        const float* wr = sw1 + i * 16;
        #pragma unroll
        for (int o = 0; o < 16; o++) h1[o] += v * wr[o];
    }

    float z100 = 100.f * h1[0];
    float sigma = (z100 > 20.f) ? h1[0] : (log1pf(expf(z100)) * 0.01f);

    float dx = dvec[3*n+0], dy = dvec[3*n+1], dz = dvec[3*n+2];
    float invn = 1.0f / sqrtf(dx*dx + dy*dy + dz*dz);
    dx *= invn; dy *= invn; dz *= invn;
    float xx = dx*dx, yy = dy*dy, zz = dz*dz;
    float xy = dx*dy, yz = dy*dz, xz = dx*dz;
    float sh[16];
    sh[0]  = 0.28209479177387814f;
    sh[1]  = -0.48860251190291987f * dy;
    sh[2]  =  0.48860251190291987f * dz;
    sh[3]  = -0.48860251190291987f * dx;
    sh[4]  =  1.0925484305920792f * xy;
    sh[5]  = -1.0925484305920792f * yz;
    sh[6]  =  0.94617469575756f * zz - 0.31539156525252005f;
    sh[7]  = -1.0925484305920792f * xz;
    sh[8]  =  0.5462742152960396f * (xx - yy);
    sh[9]  = -0.5900435899266435f * dy * (3.f * xx - yy);
    sh[10] =  2.890611442640554f * xy * dz;
    sh[11] = -0.4570457994644657f * dy * (4.f * zz - xx - yy);
    sh[12] =  0.37317633259011546f * dz * (2.f * zz - 3.f * xx - 3.f * yy);
    sh[13] = -0.4570457994644657f * dx * (4.f * zz - xx - yy);
    sh[14] =  1.445305721320277f * dz * (xx - yy);
    sh[15] = -0.5900435899266435f * dx * (xx - 3.f * yy);

    float c1[HID];
    #pragma unroll
    for (int o = 0; o < HID; o++) c1[o] = cb0[o];
    #pragma unroll
    for (int i = 0; i < 15; i++) {
        float v = h1[i + 1];
        const float* wr = cw0 + i * HID;
        #pragma unroll
        for (int o = 0; o < HID; o++) c1[o] += v * wr[o];
    }
    #pragma unroll
    for (int i = 0; i < 16; i++) {
        float v = sh[i];
        const float* wr = cw0 + (15 + i) * HID;
        #pragma unroll
        for (int o = 0; o < HID; o++) c1[o] += v * wr[o];
    }
    {
        const float4* arow = reinterpret_cast<const float4*>(app_table + (size_t)app_idx[n] * 48);
        for (int j4 = 0; j4 < 12; j4++) {
            float4 v = arow[j4];
            const float* wr = cw0 + (31 + 4 * j4) * HID;
            #pragma unroll
            for (int o = 0; o < HID; o++) c1[o] += v.x * wr[o];
            #pragma unroll
            for (int o = 0; o < HID; o++) c1[o] += v.y * wr[HID + o];
            #pragma unroll
            for (int o = 0; o < HID; o++) c1[o] += v.z * wr[2 * HID + o];
            #pragma unroll
            for (int o = 0; o < HID; o++) c1[o] += v.w * wr[3 * HID + o];
        }
    }
    #pragma unroll
    for (int o = 0; o < HID; o++) c1[o] = fmaxf(c1[o], 0.f);

    float c2[HID];
    #pragma unroll
    for (int o = 0; o < HID; o++) c2[o] = cb1[o];
    #pragma unroll
    for (int i = 0; i < HID; i++) {
        float v = c1[i];
        const float* wr = cw1 + i * HID;
        #pragma unroll
        for (int o = 0; o < HID; o++) c2[o] += v * wr[o];
    }
    #pragma unroll
    for (int o = 0; o < HID; o++) c2[o] = fmaxf(c2[o], 0.f);

    float r = cb2[0], g = cb2[1], b = cb2[2];
    #pragma unroll
    for (int i = 0; i < HID; i++) {
        float v = c2[i];
        r += v * cw2[i * 3 + 0];
        g += v * cw2[i * 3 + 1];
        b += v * cw2[i * 3 + 2];
    }
    r = 1.f / (1.f + expf(-r));
    g = 1.f / (1.f + expf(-g));
    b = 1.f / (1.f + expf(-b));

    reinterpret_cast<float4*>(out)[n] = make_float4(sigma, r, g, b);
}

extern "C" void kernel_launch(void* const* d_in, const int* in_sizes, int n_in,
                              void* d_out, int out_size, void* d_ws, size_t ws_size,
                              hipStream_t stream) {
    const float* x         = (const float*)d_in[0];
    const float* dvec      = (const float*)d_in[1];
    const int*   app_idx   = (const int*)  d_in[2];
    const float* ht        = (const float*)d_in[3];
    const float* app_table = (const float*)d_in[4];
    const float* sw0 = (const float*)d_in[5];
    const float* sb0 = (const float*)d_in[6];
    const float* sw1 = (const float*)d_in[7];
    const float* sb1 = (const float*)d_in[8];
    const float* cw0 = (const float*)d_in[9];
    const float* cb0 = (const float*)d_in[10];
    const float* cw1 = (const float*)d_in[11];
    const float* cb1 = (const float*)d_in[12];
    const float* cw2 = (const float*)d_in[13];
    const float* cb2 = (const float*)d_in[14];

    int n_pts = in_sizes[0] / 3;

    Res16 rt;
    double bb = exp(log(2048.0 / 16.0) / 15.0);
    for (int l = 0; l < NL; l++) rt.r[l] = (float)floor(16.0 * pow(bb, (double)l));

    DenseP dp;
    {
        int acc = 0;
        for (int l = 0; l < NDL; l++) {
            dp.R[l] = (int)rt.r[l] + 1;
            dp.off[l] = acc;
            acc += dp.R[l] * dp.R[l] * dp.R[l];
        }
        dp.total = acc;
    }

    const size_t tbl_entries = (size_t)NL * TBL_N;
    const size_t tbl_bytes = tbl_entries * sizeof(unsigned);       // 32 MiB
    const size_t WFRAG_OFF = tbl_bytes;
    const size_t BIAS_OFF  = WFRAG_OFF + 14336 * 2;
    const size_t DENSE_OFF = (BIAS_OFF + 224 * 4 + 255) & ~(size_t)255;
    const size_t CHUNK_OFF = (DENSE_OFF + (size_t)dp.total * 16 + 255) & ~(size_t)255;

    if (ws_size >= CHUNK_OFF + (8u << 20)) {
        int nent = (int)tbl_entries;
        hipLaunchKernelGGL(repack_bf16, dim3((nent + 255) / 256), dim3(256), 0, stream,
                           ht, (unsigned*)d_ws, nent);
        u16*   wfrag = (u16*)  ((char*)d_ws + WFRAG_OFF);
        float* biasb = (float*)((char*)d_ws + BIAS_OFF);
        uint4* dense = (uint4*)((char*)d_ws + DENSE_OFF);
        hipLaunchKernelGGL(nerf_pack_w, dim3(1), dim3(256), 0, stream,
                           sw0, sb0, sw1, sb1, cw0, cb0, cw1, cb1, cw2, cb2,
                           wfrag, biasb);
        hipLaunchKernelGGL(build_dense4, dim3((dp.total + 255) / 256), dim3(256), 0, stream,
                           (const u32*)d_ws, dense, dp);

        // chunk region: pos (16 B/pt) + enc (64 B/pt) = 80 B/pt
        size_t cap = (ws_size - CHUNK_OFF) / 80;
        if (cap > (size_t)n_pts) cap = (size_t)n_pts;
        cap &= ~(size_t)255;
        if (cap == 0) cap = 256;
        f4v* pos = (f4v*)((char*)d_ws + CHUNK_OFF);
        u32* enc = (u32*)((char*)d_ws + CHUNK_OFF + cap * 16);

        for (long p0 = 0; p0 < (long)n_pts; p0 += (long)cap) {
            int P = (int)(((long)n_pts - p0) < (long)cap ? ((long)n_pts - p0) : (long)cap);
            hipLaunchKernelGGL(pos_prep, dim3((P + 255) / 256), dim3(256), 0, stream,
                               x, pos, (int)p0, P, n_pts);
            hipLaunchKernelGGL(nerf_encode, dim3((P + 255) / 256, NL), dim3(256), 0, stream,
                               pos, (const uint4*)d_ws, dense, enc, rt, dp, P);
            hipLaunchKernelGGL(nerf_mlp_mfma, dim3((P + 255) / 256), dim3(256), 0, stream,
                               wfrag, biasb, enc,
                               dvec, app_idx, app_table,
                               (float*)d_out, (int)p0, P, n_pts);
        }
    } else if (ws_size >= tbl_bytes) {
        int nent = (int)tbl_entries;
        hipLaunchKernelGGL(repack_bf16, dim3((nent + 255) / 256), dim3(256), 0, stream,
                           ht, (unsigned*)d_ws, nent);
        dim3 g((n_pts + 255) / 256), blk(256);
        hipLaunchKernelGGL((nerf_fused<1>), g, blk, 0, stream,
                           x, dvec, app_idx, (const void*)d_ws, app_table,
                           sw0, sb0, sw1, sb1, cw0, cb0, cw1, cb1, cw2, cb2,
                           (float*)d_out, rt, n_pts);
    } else {
        dim3 g((n_pts + 255) / 256), blk(256);
        hipLaunchKernelGGL((nerf_fused<0>), g, blk, 0, stream,
                           x, dvec, app_idx, (const void*)ht, app_table,
                           sw0, sb0, sw1, sb1, cw0, cb0, cw1, cb1, cw2, cb2,
                           (float*)d_out, rt, n_pts);
    }
}